// Round 8
// baseline (306.637 us; speedup 1.0000x reference)
//
#include <hip/hip_runtime.h>
#include <hip/hip_bf16.h>
#include <math.h>

#define EMBED 384
#define HEADS 6
#define HD    64
#define NF    32
#define SEQ   1025
#define SEQP  1088   // padded key stride for Vt (17*64)
#define BATCH 16
#define MTOT  (BATCH*SEQ)   // 16400
#define NCHUNK 17
#define LSTRIDE 72   // attn P-LDS row stride (elems)
#define GSTR 40      // GEMM LDS row stride (elems)

typedef __bf16 bf16x8 __attribute__((ext_vector_type(8)));
typedef __bf16 bf16x4 __attribute__((ext_vector_type(4)));
typedef float  f32x4  __attribute__((ext_vector_type(4)));

#define MFMA_BF16(A,B,C) __builtin_amdgcn_mfma_f32_16x16x32_bf16((A),(B),(C),0,0,0)

__device__ __forceinline__ __bf16 f2bf(float f){
    __hip_bfloat16 h = __float2bfloat16(f);
    return *reinterpret_cast<__bf16*>(&h);
}

// ---------------- x fp32 -> bf16 prepass ----------------
__global__ __launch_bounds__(256) void x_to_bf16_kernel(
    const float* __restrict__ x, __hip_bfloat16* __restrict__ xb)
{
    const int n4 = MTOT*EMBED/4;
    int i = blockIdx.x*256 + threadIdx.x;
    if (i < n4){
        float4 v = *reinterpret_cast<const float4*>(x + (size_t)i*4);
        bf16x4 b; b[0]=f2bf(v.x); b[1]=f2bf(v.y); b[2]=f2bf(v.z); b[3]=f2bf(v.w);
        *reinterpret_cast<bf16x4*>(reinterpret_cast<__bf16*>(xb) + (size_t)i*4) = b;
    }
}

// ---------------- weight transpose: W fp32 [k][n] -> Wt bf16 [mat][n][k] ----
__global__ __launch_bounds__(256) void transpose_w_kernel(
    const float* __restrict__ Wq, const float* __restrict__ Wk,
    const float* __restrict__ Wv, const float* __restrict__ Wo,
    __hip_bfloat16* __restrict__ Wt)
{
    __shared__ float tile[64][65];
    const int mat = blockIdx.z;
    const float* W = (mat==0)?Wq:(mat==1)?Wk:(mat==2)?Wv:Wo;
    const int k0 = blockIdx.x*64, n0 = blockIdx.y*64;
    const int c = threadIdx.x & 63, rq = threadIdx.x >> 6;
    #pragma unroll
    for (int i = 0; i < 16; ++i){
        int row = rq*16 + i;
        tile[row][c] = W[(size_t)(k0+row)*EMBED + n0 + c];
    }
    __syncthreads();
    #pragma unroll
    for (int i = 0; i < 16; ++i){
        int nr = rq*16 + i;
        Wt[((size_t)mat*EMBED + n0 + nr)*EMBED + k0 + c] = __float2bfloat16(tile[c][nr]);
    }
}

// fp32 erfinv (Giles 2010)
__device__ __forceinline__ float erfinv_f(float x){
    float w = -log1pf(-x*x);
    float p;
    if (w < 5.0f){
        w -= 2.5f;
        p = 2.81022636e-08f;
        p = fmaf(p, w, 3.43273939e-07f);
        p = fmaf(p, w, -3.5233877e-06f);
        p = fmaf(p, w, -4.39150654e-06f);
        p = fmaf(p, w, 0.00021858087f);
        p = fmaf(p, w, -0.00125372503f);
        p = fmaf(p, w, -0.00417768164f);
        p = fmaf(p, w, 0.246640727f);
        p = fmaf(p, w, 1.50140941f);
    } else {
        w = sqrtf(w) - 3.0f;
        p = -0.000200214257f;
        p = fmaf(p, w, 0.000100950558f);
        p = fmaf(p, w, 0.00134934322f);
        p = fmaf(p, w, -0.00367342844f);
        p = fmaf(p, w, 0.00573950773f);
        p = fmaf(p, w, -0.0076224613f);
        p = fmaf(p, w, 0.00943887047f);
        p = fmaf(p, w, 1.00167406f);
        p = fmaf(p, w, 2.83297682f);
    }
    return p * x;
}

__global__ void rope_tables_kernel(float* __restrict__ cos_t, float* __restrict__ sin_t){
    int idx = blockIdx.x * blockDim.x + threadIdx.x;
    if (idx >= SEQ*HEADS*NF) return;
    int f  = idx & (NF-1);
    int hf = idx / NF;
    int h  = hf % HEADS;
    int s  = hf / HEADS;

    double xd = 2.0;
    #pragma unroll
    for (int it = 0; it < 10; ++it) xd = cbrt(1.0 + xd);
    float a1 = (float)(1.0 / xd);
    float a2 = a1 * a1;

    float fi = (float)(h*NF + f + 1);
    float z1 = fmodf(fi * a1, 1.0f);
    float z2 = fmodf(fi * a2, 1.0f);
    float d1 = erfinv_f(2.0f*z1 - 1.0f);
    float d2 = erfinv_f(2.0f*z2 - 1.0f);
    float inv = 1.0f / sqrtf(d1*d1 + d2*d2);
    d1 *= inv; d2 *= inv;

    float omega = 0.1f * powf(10000.0f, (float)f / 31.0f);
    float fx = d1 * omega, fy = d2 * omega;

    float cx = 0.0f, cy = 0.0f;
    if (s > 0){
        int pi = s - 1;
        cx = (float)(pi & 31) / 31.0f * 2.0f - 1.0f;
        cy = (float)(pi >> 5) / 31.0f * 2.0f - 1.0f;
    }
    float theta = fx*cx + fy*cy;
    float sv, cv;
    sincosf(theta, &sv, &cv);
    cos_t[idx] = cv;
    sin_t[idx] = sv;
}

// QKV: one big GEMM xb[16400x384] @ Wt[1152x384]^T, 128x128 tiles.
// q gets 1/8 * log2(e) folded in (attn uses exp2).
__global__ __launch_bounds__(256, 3) void qkv_rope_kernel(
    const __hip_bfloat16* __restrict__ xb_,
    const __hip_bfloat16* __restrict__ Wt,
    const float* __restrict__ cos_t,
    const float* __restrict__ sin_t,
    __hip_bfloat16* __restrict__ qbuf,
    __hip_bfloat16* __restrict__ kbuf,
    __hip_bfloat16* __restrict__ vbuf)
{
    __shared__ __align__(16) __bf16 xs[128*GSTR];
    __shared__ __align__(16) __bf16 bt[128*GSTR];
    const int tid = threadIdx.x;
    const int m0 = blockIdx.x * 128;
    const int j  = blockIdx.y;
    const __bf16* xb = reinterpret_cast<const __bf16*>(xb_);
    const __bf16* wt = reinterpret_cast<const __bf16*>(Wt);

    int soff[2], arow[2], brow[2];
    #pragma unroll
    for (int i = 0; i < 2; ++i){
        int g = tid + i*256;
        int row = g >> 2, kc = g & 3;
        soff[i] = row*GSTR + kc*8;
        int am = m0 + row; if (am > MTOT-1) am = MTOT-1;
        arow[i] = am;
        brow[i] = j*128 + row;
    }

    bf16x8 ar[2], br[2];
    #pragma unroll
    for (int i = 0; i < 2; ++i){
        int g = tid + i*256, kc = g & 3;
        ar[i] = *reinterpret_cast<const bf16x8*>(xb + (size_t)arow[i]*EMBED + kc*8);
        br[i] = *reinterpret_cast<const bf16x8*>(wt + (size_t)brow[i]*EMBED + kc*8);
    }

    const int w = tid >> 6;
    const int lane = tid & 63;
    const int quad = lane >> 4, low = lane & 15;
    const int mh = w >> 1, nh = w & 1;
    const int mw0 = m0 + mh*64;

    f32x4 acc[4][4] = {};
    for (int kb = 0; kb < 12; ++kb){
        __syncthreads();
        #pragma unroll
        for (int i = 0; i < 2; ++i){
            *reinterpret_cast<bf16x8*>(&xs[soff[i]]) = ar[i];
            *reinterpret_cast<bf16x8*>(&bt[soff[i]]) = br[i];
        }
        __syncthreads();
        if (kb < 11){
            const int k1 = (kb+1)*32;
            #pragma unroll
            for (int i = 0; i < 2; ++i){
                int g = tid + i*256, kc = g & 3;
                ar[i] = *reinterpret_cast<const bf16x8*>(xb + (size_t)arow[i]*EMBED + k1 + kc*8);
                br[i] = *reinterpret_cast<const bf16x8*>(wt + (size_t)brow[i]*EMBED + k1 + kc*8);
            }
        }
        bf16x8 af[4], bfr[4];
        #pragma unroll
        for (int mt = 0; mt < 4; ++mt)
            af[mt] = *reinterpret_cast<const bf16x8*>(&xs[(mh*64 + mt*16 + low)*GSTR + quad*8]);
        #pragma unroll
        for (int t = 0; t < 4; ++t)
            bfr[t] = *reinterpret_cast<const bf16x8*>(&bt[(nh*64 + t*16 + low)*GSTR + quad*8]);
        #pragma unroll
        for (int t = 0; t < 4; ++t)
            #pragma unroll
            for (int mt = 0; mt < 4; ++mt)
                acc[mt][t] = MFMA_BF16(af[mt], bfr[t], acc[mt][t]);
    }

    const int n64 = j*2 + nh;
    const int mat = n64 / 6;
    const int h   = n64 % 6;

    if (mat == 2){
        #pragma unroll
        for (int mt = 0; mt < 4; ++mt)
            #pragma unroll
            for (int t = 0; t < 4; ++t)
                #pragma unroll
                for (int r = 0; r < 4; ++r){
                    int m = mw0 + mt*16 + quad*4 + r;
                    if (m < MTOT){
                        int b = m / SEQ, s = m % SEQ;
                        vbuf[((size_t)(b*HEADS + h)*SEQ + s)*HD + t*16 + low] = __float2bfloat16(acc[mt][t][r]);
                    }
                }
    } else {
        __hip_bfloat16* ob = (mat == 0) ? qbuf : kbuf;
        const float qs_ = (mat == 0) ? 0.125f*1.44269504089f : 1.0f;   // fold log2(e) into q
        #pragma unroll
        for (int mt = 0; mt < 4; ++mt)
            #pragma unroll
            for (int t = 0; t < 2; ++t)
                #pragma unroll
                for (int r = 0; r < 4; ++r){
                    int m = mw0 + mt*16 + quad*4 + r;
                    if (m < MTOT){
                        int b = m / SEQ, s = m % SEQ;
                        int f = t*16 + low;
                        float cv = cos_t[(s*HEADS + h)*NF + f];
                        float sv = sin_t[(s*HEADS + h)*NF + f];
                        float x1 = acc[mt][t][r];
                        float y1 = acc[mt][t+2][r];
                        size_t base = ((size_t)(b*HEADS + h)*SEQ + s)*HD;
                        ob[base + f]      = __float2bfloat16((x1*cv - y1*sv)*qs_);
                        ob[base + NF + f] = __float2bfloat16((x1*sv + y1*cv)*qs_);
                    }
                }
    }
}

// V [bh][s][d] -> Vt [bh][d][SEQP]. grid (96, 17), block 256.
__global__ __launch_bounds__(256) void vt_transpose_kernel(
    const __hip_bfloat16* __restrict__ v, __hip_bfloat16* __restrict__ vt)
{
    __shared__ __bf16 tileT[64*72];
    const int tid = threadIdx.x;
    const int bh = blockIdx.x;
    const int s0 = blockIdx.y * 64;
    const __bf16* vb = reinterpret_cast<const __bf16*>(v) + (size_t)bh*SEQ*HD;
    #pragma unroll
    for (int i = 0; i < 2; ++i){
        int ch = tid + i*256;
        int srow = ch >> 3, dg = ch & 7;
        int s = s0 + srow; if (s > SEQ-1) s = SEQ-1;
        bf16x8 val = *reinterpret_cast<const bf16x8*>(vb + (size_t)s*HD + dg*8);
        #pragma unroll
        for (int e = 0; e < 8; ++e)
            tileT[(dg*8 + e)*72 + srow] = val[e];
    }
    __syncthreads();
    __bf16* ot = reinterpret_cast<__bf16*>(vt) + (size_t)bh*HD*SEQP;
    #pragma unroll
    for (int i = 0; i < 2; ++i){
        int ch = tid + i*256;
        int d = ch >> 3, sg = ch & 7;
        bf16x8 val = *reinterpret_cast<const bf16x8*>(&tileT[d*72 + sg*8]);
        *reinterpret_cast<bf16x8*>(ot + (size_t)d*SEQP + s0 + sg*8) = val;
    }
}

// Flash attention, barrier-free: K/V fragments loaded per-wave direct from
// global (L2-resident via id%96 swizzle); only the P transpose uses LDS
// (wave-private). Fixed-base softmax with exp2 (log2e folded into q).
__global__ __launch_bounds__(256, 4) void attn_kernel(
    const __hip_bfloat16* __restrict__ qbuf,
    const __hip_bfloat16* __restrict__ kbuf,
    const __hip_bfloat16* __restrict__ vtbuf,
    __hip_bfloat16* __restrict__ aout)
{
    __shared__ __align__(16) __bf16 pls[4][32*LSTRIDE]; // [w][qrow][key]
    const int tid  = threadIdx.x;
    const int w    = tid >> 6;
    const int lane = tid & 63;
    const int quad = lane >> 4, low = lane & 15;
    const int id = blockIdx.x;
    const int bh = id % 96;
    const int qt = id / 96;
    const int b = bh / HEADS, h = bh % HEADS;
    const __bf16* qb = reinterpret_cast<const __bf16*>(qbuf);
    const __bf16* kb = reinterpret_cast<const __bf16*>(kbuf);
    const __bf16* vt = reinterpret_cast<const __bf16*>(vtbuf);
    const size_t base   = (size_t)bh * SEQ * HD;
    const size_t vtbase = (size_t)bh * HD * SEQP;
    const int q0 = qt*128 + w*32;

    bf16x8 bq[2][2];
    #pragma unroll
    for (int nt = 0; nt < 2; ++nt){
        int qs = q0 + nt*16 + low; if (qs > SEQ-1) qs = SEQ-1;
        #pragma unroll
        for (int ks = 0; ks < 2; ++ks)
            bq[nt][ks] = *reinterpret_cast<const bf16x8*>(qb + base + (size_t)qs*HD + ks*32 + quad*8);
    }

    f32x4 o[4][2] = {};
    float l_i[2] = {0.f, 0.f};

    for (int c = 0; c < NCHUNK; ++c){
        const int c0 = c*64;
        // ---- K fragments direct from global: A[m=key][k=feat]
        bf16x8 kf[4][2];
        #pragma unroll
        for (int kt = 0; kt < 4; ++kt)
            #pragma unroll
            for (int ks = 0; ks < 2; ++ks)
                kf[kt][ks] = *reinterpret_cast<const bf16x8*>(
                    kb + base + (size_t)(c0 + kt*16 + low)*HD + ks*32 + quad*8);
        f32x4 st[4][2] = {};
        #pragma unroll
        for (int kt = 0; kt < 4; ++kt)
            #pragma unroll
            for (int ks = 0; ks < 2; ++ks)
                #pragma unroll
                for (int nt = 0; nt < 2; ++nt)
                    st[kt][nt] = MFMA_BF16(kf[kt][ks], bq[nt][ks], st[kt][nt]);
        // ---- V fragments (issue early): A[m=d][k=key]
        bf16x8 vf[4][2];
        #pragma unroll
        for (int dt = 0; dt < 4; ++dt)
            #pragma unroll
            for (int ks2 = 0; ks2 < 2; ++ks2)
                vf[dt][ks2] = *reinterpret_cast<const bf16x8*>(
                    vt + vtbase + (size_t)(dt*16 + low)*SEQP + c0 + ks2*32 + quad*8);
        // ---- mask (last chunk only)
        if (c0 + 64 > SEQ){
            #pragma unroll
            for (int kt = 0; kt < 4; ++kt)
                #pragma unroll
                for (int r = 0; r < 4; ++r){
                    int key = c0 + kt*16 + quad*4 + r;
                    if (key >= SEQ){ st[kt][0][r] = -1e30f; st[kt][1][r] = -1e30f; }
                }
        }
        // ---- exp2 + tree-reduced l partial
        #pragma unroll
        for (int nt = 0; nt < 2; ++nt){
            #pragma unroll
            for (int kt = 0; kt < 4; ++kt)
                #pragma unroll
                for (int r = 0; r < 4; ++r)
                    st[kt][nt][r] = exp2f(st[kt][nt][r]);
            f32x4 ps = st[0][nt] + st[1][nt];
            f32x4 ps2 = st[2][nt] + st[3][nt];
            ps = ps + ps2;
            l_i[nt] += (ps[0] + ps[1]) + (ps[2] + ps[3]);
        }
        // ---- P^T -> per-wave LDS
        #pragma unroll
        for (int nt = 0; nt < 2; ++nt)
            #pragma unroll
            for (int kt = 0; kt < 4; ++kt){
                bf16x4 pk;
                pk[0] = f2bf(st[kt][nt][0]); pk[1] = f2bf(st[kt][nt][1]);
                pk[2] = f2bf(st[kt][nt][2]); pk[3] = f2bf(st[kt][nt][3]);
                *reinterpret_cast<bf16x4*>(&pls[w][(nt*16 + low)*LSTRIDE + kt*16 + quad*4]) = pk;
            }
        asm volatile("s_waitcnt lgkmcnt(0)" ::: "memory");
        // ---- O^T += Vt.P^T
        #pragma unroll
        for (int ks2 = 0; ks2 < 2; ++ks2){
            bf16x8 bp[2];
            #pragma unroll
            for (int nt = 0; nt < 2; ++nt)
                bp[nt] = *reinterpret_cast<const bf16x8*>(&pls[w][(nt*16 + low)*LSTRIDE + ks2*32 + quad*8]);
            #pragma unroll
            for (int dt = 0; dt < 4; ++dt)
                #pragma unroll
                for (int nt = 0; nt < 2; ++nt)
                    o[dt][nt] = MFMA_BF16(vf[dt][ks2], bp[nt], o[dt][nt]);
        }
    }

    #pragma unroll
    for (int nt = 0; nt < 2; ++nt){
        l_i[nt] += __shfl_xor(l_i[nt], 16, 64);
        l_i[nt] += __shfl_xor(l_i[nt], 32, 64);
    }
    #pragma unroll
    for (int nt = 0; nt < 2; ++nt){
        int s = q0 + nt*16 + low;
        if (s < SEQ){
            float inv = 1.0f / l_i[nt];
            #pragma unroll
            for (int dt = 0; dt < 4; ++dt){
                bf16x4 ov;
                #pragma unroll
                for (int r = 0; r < 4; ++r) ov[r] = f2bf(o[dt][nt][r]*inv);
                *reinterpret_cast<bf16x4*>(
                    reinterpret_cast<__bf16*>(aout) + ((size_t)b*SEQ + s)*EMBED + h*HD + dt*16 + quad*4) = ov;
            }
        }
    }
}

// out = attn @ Wo + bo, 128x128 tiles. grid (129, 3), block 256.
__global__ __launch_bounds__(256, 3) void outproj_kernel(
    const __hip_bfloat16* __restrict__ a,
    const __hip_bfloat16* __restrict__ Wt,
    const float* __restrict__ bo,
    float* __restrict__ out)
{
    __shared__ __align__(16) __bf16 xs[128*GSTR];
    __shared__ __align__(16) __bf16 bt[128*GSTR];
    const int tid = threadIdx.x;
    const int m0 = blockIdx.x * 128;
    const int j  = blockIdx.y;
    const __bf16* ab = reinterpret_cast<const __bf16*>(a);
    const __bf16* wt = reinterpret_cast<const __bf16*>(Wt) + (size_t)3*EMBED*EMBED;

    int soff[2], arow[2], brow[2];
    #pragma unroll
    for (int i = 0; i < 2; ++i){
        int g = tid + i*256;
        int row = g >> 2, kc = g & 3;
        soff[i] = row*GSTR + kc*8;
        int am = m0 + row; if (am > MTOT-1) am = MTOT-1;
        arow[i] = am;
        brow[i] = j*128 + row;
    }
    bf16x8 ar[2], br[2];
    #pragma unroll
    for (int i = 0; i < 2; ++i){
        int g = tid + i*256, kc = g & 3;
        ar[i] = *reinterpret_cast<const bf16x8*>(ab + (size_t)arow[i]*EMBED + kc*8);
        br[i] = *reinterpret_cast<const bf16x8*>(wt + (size_t)brow[i]*EMBED + kc*8);
    }

    const int w = tid >> 6;
    const int lane = tid & 63;
    const int quad = lane >> 4, low = lane & 15;
    const int mh = w >> 1, nh = w & 1;
    const int mw0 = m0 + mh*64;
    const int n0 = j*128 + nh*64;

    f32x4 acc[4][4] = {};
    for (int kb = 0; kb < 12; ++kb){
        __syncthreads();
        #pragma unroll
        for (int i = 0; i < 2; ++i){
            *reinterpret_cast<bf16x8*>(&xs[soff[i]]) = ar[i];
            *reinterpret_cast<bf16x8*>(&bt[soff[i]]) = br[i];
        }
        __syncthreads();
        if (kb < 11){
            const int k1 = (kb+1)*32;
            #pragma unroll
            for (int i = 0; i < 2; ++i){
                int g = tid + i*256, kc = g & 3;
                ar[i] = *reinterpret_cast<const bf16x8*>(ab + (size_t)arow[i]*EMBED + k1 + kc*8);
                br[i] = *reinterpret_cast<const bf16x8*>(wt + (size_t)brow[i]*EMBED + k1 + kc*8);
            }
        }
        bf16x8 af[4], bfr[4];
        #pragma unroll
        for (int mt = 0; mt < 4; ++mt)
            af[mt] = *reinterpret_cast<const bf16x8*>(&xs[(mh*64 + mt*16 + low)*GSTR + quad*8]);
        #pragma unroll
        for (int t = 0; t < 4; ++t)
            bfr[t] = *reinterpret_cast<const bf16x8*>(&bt[(nh*64 + t*16 + low)*GSTR + quad*8]);
        #pragma unroll
        for (int t = 0; t < 4; ++t)
            #pragma unroll
            for (int mt = 0; mt < 4; ++mt)
                acc[mt][t] = MFMA_BF16(af[mt], bfr[t], acc[mt][t]);
    }

    #pragma unroll
    for (int t = 0; t < 4; ++t){
        const int n = n0 + t*16 + low;
        const float bias = bo[n];
        #pragma unroll
        for (int mt = 0; mt < 4; ++mt)
            #pragma unroll
            for (int r = 0; r < 4; ++r){
                const int m = mw0 + mt*16 + quad*4 + r;
                if (m < MTOT) out[(size_t)m*EMBED + n] = acc[mt][t][r] + bias;
            }
    }
}

extern "C" void kernel_launch(void* const* d_in, const int* in_sizes, int n_in,
                              void* d_out, int out_size, void* d_ws, size_t ws_size,
                              hipStream_t stream)
{
    const float* x  = (const float*)d_in[0];
    const float* Wq = (const float*)d_in[1];
    const float* Wk = (const float*)d_in[2];
    const float* Wv = (const float*)d_in[3];
    const float* Wo = (const float*)d_in[4];
    const float* bo = (const float*)d_in[5];
    float* out = (float*)d_out;

    const size_t NE = (size_t)MTOT * EMBED;
    const size_t VT = (size_t)BATCH*HEADS*HD*SEQP;
    char* ws = (char*)d_ws;
    size_t off = 0;
    __hip_bfloat16* qbuf = (__hip_bfloat16*)(ws + off); off += 2*NE;
    __hip_bfloat16* kbuf = (__hip_bfloat16*)(ws + off); off += 2*NE;
    __hip_bfloat16* abuf = (__hip_bfloat16*)(ws + off); off += 2*NE;
    __hip_bfloat16* vbuf = (__hip_bfloat16*)(ws + off); off += 2*NE;
    __hip_bfloat16* xbuf = (__hip_bfloat16*)(ws + off); off += 2*NE;
    __hip_bfloat16* vt   = (__hip_bfloat16*)(ws + off); off += 2*VT;
    __hip_bfloat16* Wt   = (__hip_bfloat16*)(ws + off); off += (size_t)4*EMBED*EMBED*2;
    float* cos_t = (float*)(ws + off); off += (size_t)SEQ*HEADS*NF*4;
    float* sin_t = (float*)(ws + off); off += (size_t)SEQ*HEADS*NF*4;

    x_to_bf16_kernel<<<dim3((MTOT*EMBED/4 + 255)/256), dim3(256), 0, stream>>>(x, xbuf);
    transpose_w_kernel<<<dim3(6,6,4), dim3(256), 0, stream>>>(Wq, Wk, Wv, Wo, Wt);
    rope_tables_kernel<<<dim3((SEQ*HEADS*NF + 255)/256), dim3(256), 0, stream>>>(cos_t, sin_t);
    qkv_rope_kernel<<<dim3((MTOT + 127)/128, 9), dim3(256), 0, stream>>>(xbuf, Wt, cos_t, sin_t, qbuf, kbuf, vbuf);
    vt_transpose_kernel<<<dim3(96, 17), dim3(256), 0, stream>>>(vbuf, vt);
    attn_kernel<<<dim3(864), dim3(256), 0, stream>>>(qbuf, kbuf, vt, abuf);
    outproj_kernel<<<dim3((MTOT + 127)/128, 3), dim3(256), 0, stream>>>(abuf, Wt, bo, out);
}

// Round 9
// 284.379 us; speedup vs baseline: 1.0783x; 1.0783x over previous
//
#include <hip/hip_runtime.h>
#include <hip/hip_bf16.h>
#include <math.h>

#define EMBED 384
#define HEADS 6
#define HD    64
#define NF    32
#define SEQ   1025
#define SEQP  1088   // padded key stride for Vt (17*64)
#define BATCH 16
#define MTOT  (BATCH*SEQ)   // 16400
#define NCHUNK 17
#define LSTRIDE 72   // attn P-LDS row stride (elems)
#define GSTR 40      // GEMM LDS row stride (elems)

typedef __bf16 bf16x8 __attribute__((ext_vector_type(8)));
typedef __bf16 bf16x4 __attribute__((ext_vector_type(4)));
typedef float  f32x4  __attribute__((ext_vector_type(4)));

#define MFMA_BF16(A,B,C) __builtin_amdgcn_mfma_f32_16x16x32_bf16((A),(B),(C),0,0,0)

__device__ __forceinline__ __bf16 f2bf(float f){
    __hip_bfloat16 h = __float2bfloat16(f);
    return *reinterpret_cast<__bf16*>(&h);
}

// ---------------- x fp32 -> bf16 prepass ----------------
__global__ __launch_bounds__(256) void x_to_bf16_kernel(
    const float* __restrict__ x, __hip_bfloat16* __restrict__ xb)
{
    const int n4 = MTOT*EMBED/4;
    int i = blockIdx.x*256 + threadIdx.x;
    if (i < n4){
        float4 v = *reinterpret_cast<const float4*>(x + (size_t)i*4);
        bf16x4 b; b[0]=f2bf(v.x); b[1]=f2bf(v.y); b[2]=f2bf(v.z); b[3]=f2bf(v.w);
        *reinterpret_cast<bf16x4*>(reinterpret_cast<__bf16*>(xb) + (size_t)i*4) = b;
    }
}

// ---------------- weight transpose: W fp32 [k][n] -> Wt bf16 [mat][n][k] ----
__global__ __launch_bounds__(256) void transpose_w_kernel(
    const float* __restrict__ Wq, const float* __restrict__ Wk,
    const float* __restrict__ Wv, const float* __restrict__ Wo,
    __hip_bfloat16* __restrict__ Wt)
{
    __shared__ float tile[64][65];
    const int mat = blockIdx.z;
    const float* W = (mat==0)?Wq:(mat==1)?Wk:(mat==2)?Wv:Wo;
    const int k0 = blockIdx.x*64, n0 = blockIdx.y*64;
    const int c = threadIdx.x & 63, rq = threadIdx.x >> 6;
    #pragma unroll
    for (int i = 0; i < 16; ++i){
        int row = rq*16 + i;
        tile[row][c] = W[(size_t)(k0+row)*EMBED + n0 + c];
    }
    __syncthreads();
    #pragma unroll
    for (int i = 0; i < 16; ++i){
        int nr = rq*16 + i;
        Wt[((size_t)mat*EMBED + n0 + nr)*EMBED + k0 + c] = __float2bfloat16(tile[c][nr]);
    }
}

// fp32 erfinv (Giles 2010)
__device__ __forceinline__ float erfinv_f(float x){
    float w = -log1pf(-x*x);
    float p;
    if (w < 5.0f){
        w -= 2.5f;
        p = 2.81022636e-08f;
        p = fmaf(p, w, 3.43273939e-07f);
        p = fmaf(p, w, -3.5233877e-06f);
        p = fmaf(p, w, -4.39150654e-06f);
        p = fmaf(p, w, 0.00021858087f);
        p = fmaf(p, w, -0.00125372503f);
        p = fmaf(p, w, -0.00417768164f);
        p = fmaf(p, w, 0.246640727f);
        p = fmaf(p, w, 1.50140941f);
    } else {
        w = sqrtf(w) - 3.0f;
        p = -0.000200214257f;
        p = fmaf(p, w, 0.000100950558f);
        p = fmaf(p, w, 0.00134934322f);
        p = fmaf(p, w, -0.00367342844f);
        p = fmaf(p, w, 0.00573950773f);
        p = fmaf(p, w, -0.0076224613f);
        p = fmaf(p, w, 0.00943887047f);
        p = fmaf(p, w, 1.00167406f);
        p = fmaf(p, w, 2.83297682f);
    }
    return p * x;
}

__global__ void rope_tables_kernel(float* __restrict__ cos_t, float* __restrict__ sin_t){
    int idx = blockIdx.x * blockDim.x + threadIdx.x;
    if (idx >= SEQ*HEADS*NF) return;
    int f  = idx & (NF-1);
    int hf = idx / NF;
    int h  = hf % HEADS;
    int s  = hf / HEADS;

    double xd = 2.0;
    #pragma unroll
    for (int it = 0; it < 10; ++it) xd = cbrt(1.0 + xd);
    float a1 = (float)(1.0 / xd);
    float a2 = a1 * a1;

    float fi = (float)(h*NF + f + 1);
    float z1 = fmodf(fi * a1, 1.0f);
    float z2 = fmodf(fi * a2, 1.0f);
    float d1 = erfinv_f(2.0f*z1 - 1.0f);
    float d2 = erfinv_f(2.0f*z2 - 1.0f);
    float inv = 1.0f / sqrtf(d1*d1 + d2*d2);
    d1 *= inv; d2 *= inv;

    float omega = 0.1f * powf(10000.0f, (float)f / 31.0f);
    float fx = d1 * omega, fy = d2 * omega;

    float cx = 0.0f, cy = 0.0f;
    if (s > 0){
        int pi = s - 1;
        cx = (float)(pi & 31) / 31.0f * 2.0f - 1.0f;
        cy = (float)(pi >> 5) / 31.0f * 2.0f - 1.0f;
    }
    float theta = fx*cx + fy*cy;
    float sv, cv;
    sincosf(theta, &sv, &cv);
    cos_t[idx] = cv;
    sin_t[idx] = sv;
}

// QKV: one big GEMM xb[16400x384] @ Wt[1152x384]^T, 128x128 tiles.
// q gets 1/8 * log2(e) folded in (attn uses exp2).
__global__ __launch_bounds__(256, 3) void qkv_rope_kernel(
    const __hip_bfloat16* __restrict__ xb_,
    const __hip_bfloat16* __restrict__ Wt,
    const float* __restrict__ cos_t,
    const float* __restrict__ sin_t,
    __hip_bfloat16* __restrict__ qbuf,
    __hip_bfloat16* __restrict__ kbuf,
    __hip_bfloat16* __restrict__ vbuf)
{
    __shared__ __align__(16) __bf16 xs[128*GSTR];
    __shared__ __align__(16) __bf16 bt[128*GSTR];
    const int tid = threadIdx.x;
    const int m0 = blockIdx.x * 128;
    const int j  = blockIdx.y;
    const __bf16* xb = reinterpret_cast<const __bf16*>(xb_);
    const __bf16* wt = reinterpret_cast<const __bf16*>(Wt);

    int soff[2], arow[2], brow[2];
    #pragma unroll
    for (int i = 0; i < 2; ++i){
        int g = tid + i*256;
        int row = g >> 2, kc = g & 3;
        soff[i] = row*GSTR + kc*8;
        int am = m0 + row; if (am > MTOT-1) am = MTOT-1;
        arow[i] = am;
        brow[i] = j*128 + row;
    }

    bf16x8 ar[2], br[2];
    #pragma unroll
    for (int i = 0; i < 2; ++i){
        int g = tid + i*256, kc = g & 3;
        ar[i] = *reinterpret_cast<const bf16x8*>(xb + (size_t)arow[i]*EMBED + kc*8);
        br[i] = *reinterpret_cast<const bf16x8*>(wt + (size_t)brow[i]*EMBED + kc*8);
    }

    const int w = tid >> 6;
    const int lane = tid & 63;
    const int quad = lane >> 4, low = lane & 15;
    const int mh = w >> 1, nh = w & 1;
    const int mw0 = m0 + mh*64;

    f32x4 acc[4][4] = {};
    for (int kb = 0; kb < 12; ++kb){
        __syncthreads();
        #pragma unroll
        for (int i = 0; i < 2; ++i){
            *reinterpret_cast<bf16x8*>(&xs[soff[i]]) = ar[i];
            *reinterpret_cast<bf16x8*>(&bt[soff[i]]) = br[i];
        }
        __syncthreads();
        if (kb < 11){
            const int k1 = (kb+1)*32;
            #pragma unroll
            for (int i = 0; i < 2; ++i){
                int g = tid + i*256, kc = g & 3;
                ar[i] = *reinterpret_cast<const bf16x8*>(xb + (size_t)arow[i]*EMBED + k1 + kc*8);
                br[i] = *reinterpret_cast<const bf16x8*>(wt + (size_t)brow[i]*EMBED + k1 + kc*8);
            }
        }
        bf16x8 af[4], bfr[4];
        #pragma unroll
        for (int mt = 0; mt < 4; ++mt)
            af[mt] = *reinterpret_cast<const bf16x8*>(&xs[(mh*64 + mt*16 + low)*GSTR + quad*8]);
        #pragma unroll
        for (int t = 0; t < 4; ++t)
            bfr[t] = *reinterpret_cast<const bf16x8*>(&bt[(nh*64 + t*16 + low)*GSTR + quad*8]);
        #pragma unroll
        for (int t = 0; t < 4; ++t)
            #pragma unroll
            for (int mt = 0; mt < 4; ++mt)
                acc[mt][t] = MFMA_BF16(af[mt], bfr[t], acc[mt][t]);
    }

    const int n64 = j*2 + nh;
    const int mat = n64 / 6;
    const int h   = n64 % 6;

    if (mat == 2){
        #pragma unroll
        for (int mt = 0; mt < 4; ++mt)
            #pragma unroll
            for (int t = 0; t < 4; ++t)
                #pragma unroll
                for (int r = 0; r < 4; ++r){
                    int m = mw0 + mt*16 + quad*4 + r;
                    if (m < MTOT){
                        int b = m / SEQ, s = m % SEQ;
                        vbuf[((size_t)(b*HEADS + h)*SEQ + s)*HD + t*16 + low] = __float2bfloat16(acc[mt][t][r]);
                    }
                }
    } else {
        __hip_bfloat16* ob = (mat == 0) ? qbuf : kbuf;
        const float qs_ = (mat == 0) ? 0.125f*1.44269504089f : 1.0f;
        #pragma unroll
        for (int mt = 0; mt < 4; ++mt)
            #pragma unroll
            for (int t = 0; t < 2; ++t)
                #pragma unroll
                for (int r = 0; r < 4; ++r){
                    int m = mw0 + mt*16 + quad*4 + r;
                    if (m < MTOT){
                        int b = m / SEQ, s = m % SEQ;
                        int f = t*16 + low;
                        float cv = cos_t[(s*HEADS + h)*NF + f];
                        float sv = sin_t[(s*HEADS + h)*NF + f];
                        float x1 = acc[mt][t][r];
                        float y1 = acc[mt][t+2][r];
                        size_t base = ((size_t)(b*HEADS + h)*SEQ + s)*HD;
                        ob[base + f]      = __float2bfloat16((x1*cv - y1*sv)*qs_);
                        ob[base + NF + f] = __float2bfloat16((x1*sv + y1*cv)*qs_);
                    }
                }
    }
}

// V [bh][s][d] -> Vt [bh][d][SEQP]. grid (96, 17), block 256.
__global__ __launch_bounds__(256) void vt_transpose_kernel(
    const __hip_bfloat16* __restrict__ v, __hip_bfloat16* __restrict__ vt)
{
    __shared__ __bf16 tileT[64*72];
    const int tid = threadIdx.x;
    const int bh = blockIdx.x;
    const int s0 = blockIdx.y * 64;
    const __bf16* vb = reinterpret_cast<const __bf16*>(v) + (size_t)bh*SEQ*HD;
    #pragma unroll
    for (int i = 0; i < 2; ++i){
        int ch = tid + i*256;
        int srow = ch >> 3, dg = ch & 7;
        int s = s0 + srow; if (s > SEQ-1) s = SEQ-1;
        bf16x8 val = *reinterpret_cast<const bf16x8*>(vb + (size_t)s*HD + dg*8);
        #pragma unroll
        for (int e = 0; e < 8; ++e)
            tileT[(dg*8 + e)*72 + srow] = val[e];
    }
    __syncthreads();
    __bf16* ot = reinterpret_cast<__bf16*>(vt) + (size_t)bh*HD*SEQP;
    #pragma unroll
    for (int i = 0; i < 2; ++i){
        int ch = tid + i*256;
        int d = ch >> 3, sg = ch & 7;
        bf16x8 val = *reinterpret_cast<const bf16x8*>(&tileT[d*72 + sg*8]);
        *reinterpret_cast<bf16x8*>(ot + (size_t)d*SEQP + s0 + sg*8) = val;
    }
}

// Flash attention, barrier-free, register-double-buffered direct-global K/V.
// K frags for c+1 issued right after S^T consumes kf (softmax+PV cover);
// V frags for c+1 issued after PV (next S^T+softmax cover). P-only LDS.
__global__ __launch_bounds__(256) void attn_kernel(
    const __hip_bfloat16* __restrict__ qbuf,
    const __hip_bfloat16* __restrict__ kbuf,
    const __hip_bfloat16* __restrict__ vtbuf,
    __hip_bfloat16* __restrict__ aout)
{
    __shared__ __align__(16) __bf16 pls[4][32*LSTRIDE]; // [w][qrow][key]
    const int tid  = threadIdx.x;
    const int w    = tid >> 6;
    const int lane = tid & 63;
    const int quad = lane >> 4, low = lane & 15;
    const int id = blockIdx.x;
    const int bh = id % 96;
    const int qt = id / 96;
    const int b = bh / HEADS, h = bh % HEADS;
    const __bf16* qb = reinterpret_cast<const __bf16*>(qbuf);
    const __bf16* kb = reinterpret_cast<const __bf16*>(kbuf);
    const __bf16* vt = reinterpret_cast<const __bf16*>(vtbuf);
    const size_t base   = (size_t)bh * SEQ * HD;
    const size_t vtbase = (size_t)bh * HD * SEQP;
    const int q0 = qt*128 + w*32;

    bf16x8 bq[2][2];
    #pragma unroll
    for (int nt = 0; nt < 2; ++nt){
        int qs = q0 + nt*16 + low; if (qs > SEQ-1) qs = SEQ-1;
        #pragma unroll
        for (int ks = 0; ks < 2; ++ks)
            bq[nt][ks] = *reinterpret_cast<const bf16x8*>(qb + base + (size_t)qs*HD + ks*32 + quad*8);
    }

    // prefetch chunk 0 K and V fragments into registers
    bf16x8 kf[4][2], vf[4][2];
    #pragma unroll
    for (int kt = 0; kt < 4; ++kt)
        #pragma unroll
        for (int ks = 0; ks < 2; ++ks)
            kf[kt][ks] = *reinterpret_cast<const bf16x8*>(
                kb + base + (size_t)(kt*16 + low)*HD + ks*32 + quad*8);
    #pragma unroll
    for (int dt = 0; dt < 4; ++dt)
        #pragma unroll
        for (int ks2 = 0; ks2 < 2; ++ks2)
            vf[dt][ks2] = *reinterpret_cast<const bf16x8*>(
                vt + vtbase + (size_t)(dt*16 + low)*SEQP + ks2*32 + quad*8);

    f32x4 o[4][2] = {};
    float l_i[2] = {0.f, 0.f};

    #pragma unroll 1
    for (int c = 0; c < NCHUNK; ++c){
        const int c0 = c*64;
        const int c1 = c0 + 64;
        // ---- S^T = K.Q^T (consumes kf)
        f32x4 st[4][2] = {};
        #pragma unroll
        for (int kt = 0; kt < 4; ++kt)
            #pragma unroll
            for (int ks = 0; ks < 2; ++ks)
                #pragma unroll
                for (int nt = 0; nt < 2; ++nt)
                    st[kt][nt] = MFMA_BF16(kf[kt][ks], bq[nt][ks], st[kt][nt]);
        // ---- prefetch next-chunk K (kf dead; cover = softmax + PV)
        if (c + 1 < NCHUNK){
            #pragma unroll
            for (int kt = 0; kt < 4; ++kt)
                #pragma unroll
                for (int ks = 0; ks < 2; ++ks)
                    kf[kt][ks] = *reinterpret_cast<const bf16x8*>(
                        kb + base + (size_t)(c1 + kt*16 + low)*HD + ks*32 + quad*8);
        }
        // ---- mask (last chunk only)
        if (c0 + 64 > SEQ){
            #pragma unroll
            for (int kt = 0; kt < 4; ++kt)
                #pragma unroll
                for (int r = 0; r < 4; ++r){
                    int key = c0 + kt*16 + quad*4 + r;
                    if (key >= SEQ){ st[kt][0][r] = -1e30f; st[kt][1][r] = -1e30f; }
                }
        }
        // ---- exp2 + tree-reduced l partial
        #pragma unroll
        for (int nt = 0; nt < 2; ++nt){
            #pragma unroll
            for (int kt = 0; kt < 4; ++kt)
                #pragma unroll
                for (int r = 0; r < 4; ++r)
                    st[kt][nt][r] = exp2f(st[kt][nt][r]);
            f32x4 ps = st[0][nt] + st[1][nt];
            f32x4 ps2 = st[2][nt] + st[3][nt];
            ps = ps + ps2;
            l_i[nt] += (ps[0] + ps[1]) + (ps[2] + ps[3]);
        }
        // ---- P^T -> per-wave LDS
        #pragma unroll
        for (int nt = 0; nt < 2; ++nt)
            #pragma unroll
            for (int kt = 0; kt < 4; ++kt){
                bf16x4 pk;
                pk[0] = f2bf(st[kt][nt][0]); pk[1] = f2bf(st[kt][nt][1]);
                pk[2] = f2bf(st[kt][nt][2]); pk[3] = f2bf(st[kt][nt][3]);
                *reinterpret_cast<bf16x4*>(&pls[w][(nt*16 + low)*LSTRIDE + kt*16 + quad*4]) = pk;
            }
        asm volatile("s_waitcnt lgkmcnt(0)" ::: "memory");
        // ---- O^T += Vt.P^T (consumes vf)
        #pragma unroll
        for (int ks2 = 0; ks2 < 2; ++ks2){
            bf16x8 bp[2];
            #pragma unroll
            for (int nt = 0; nt < 2; ++nt)
                bp[nt] = *reinterpret_cast<const bf16x8*>(&pls[w][(nt*16 + low)*LSTRIDE + ks2*32 + quad*8]);
            #pragma unroll
            for (int dt = 0; dt < 4; ++dt)
                #pragma unroll
                for (int nt = 0; nt < 2; ++nt)
                    o[dt][nt] = MFMA_BF16(vf[dt][ks2], bp[nt], o[dt][nt]);
        }
        // ---- prefetch next-chunk V (vf dead; cover = next S^T + softmax)
        if (c + 1 < NCHUNK){
            #pragma unroll
            for (int dt = 0; dt < 4; ++dt)
                #pragma unroll
                for (int ks2 = 0; ks2 < 2; ++ks2)
                    vf[dt][ks2] = *reinterpret_cast<const bf16x8*>(
                        vt + vtbase + (size_t)(dt*16 + low)*SEQP + c1 + ks2*32 + quad*8);
        }
    }

    #pragma unroll
    for (int nt = 0; nt < 2; ++nt){
        l_i[nt] += __shfl_xor(l_i[nt], 16, 64);
        l_i[nt] += __shfl_xor(l_i[nt], 32, 64);
    }
    #pragma unroll
    for (int nt = 0; nt < 2; ++nt){
        int s = q0 + nt*16 + low;
        if (s < SEQ){
            float inv = 1.0f / l_i[nt];
            #pragma unroll
            for (int dt = 0; dt < 4; ++dt){
                bf16x4 ov;
                #pragma unroll
                for (int r = 0; r < 4; ++r) ov[r] = f2bf(o[dt][nt][r]*inv);
                *reinterpret_cast<bf16x4*>(
                    reinterpret_cast<__bf16*>(aout) + ((size_t)b*SEQ + s)*EMBED + h*HD + dt*16 + quad*4) = ov;
            }
        }
    }
}

// out = attn @ Wo + bo, 128x128 tiles. grid (129, 3), block 256.
__global__ __launch_bounds__(256, 3) void outproj_kernel(
    const __hip_bfloat16* __restrict__ a,
    const __hip_bfloat16* __restrict__ Wt,
    const float* __restrict__ bo,
    float* __restrict__ out)
{
    __shared__ __align__(16) __bf16 xs[128*GSTR];
    __shared__ __align__(16) __bf16 bt[128*GSTR];
    const int tid = threadIdx.x;
    const int m0 = blockIdx.x * 128;
    const int j  = blockIdx.y;
    const __bf16* ab = reinterpret_cast<const __bf16*>(a);
    const __bf16* wt = reinterpret_cast<const __bf16*>(Wt) + (size_t)3*EMBED*EMBED;

    int soff[2], arow[2], brow[2];
    #pragma unroll
    for (int i = 0; i < 2; ++i){
        int g = tid + i*256;
        int row = g >> 2, kc = g & 3;
        soff[i] = row*GSTR + kc*8;
        int am = m0 + row; if (am > MTOT-1) am = MTOT-1;
        arow[i] = am;
        brow[i] = j*128 + row;
    }
    bf16x8 ar[2], br[2];
    #pragma unroll
    for (int i = 0; i < 2; ++i){
        int g = tid + i*256, kc = g & 3;
        ar[i] = *reinterpret_cast<const bf16x8*>(ab + (size_t)arow[i]*EMBED + kc*8);
        br[i] = *reinterpret_cast<const bf16x8*>(wt + (size_t)brow[i]*EMBED + kc*8);
    }

    const int w = tid >> 6;
    const int lane = tid & 63;
    const int quad = lane >> 4, low = lane & 15;
    const int mh = w >> 1, nh = w & 1;
    const int mw0 = m0 + mh*64;
    const int n0 = j*128 + nh*64;

    f32x4 acc[4][4] = {};
    for (int kb = 0; kb < 12; ++kb){
        __syncthreads();
        #pragma unroll
        for (int i = 0; i < 2; ++i){
            *reinterpret_cast<bf16x8*>(&xs[soff[i]]) = ar[i];
            *reinterpret_cast<bf16x8*>(&bt[soff[i]]) = br[i];
        }
        __syncthreads();
        if (kb < 11){
            const int k1 = (kb+1)*32;
            #pragma unroll
            for (int i = 0; i < 2; ++i){
                int g = tid + i*256, kc = g & 3;
                ar[i] = *reinterpret_cast<const bf16x8*>(ab + (size_t)arow[i]*EMBED + k1 + kc*8);
                br[i] = *reinterpret_cast<const bf16x8*>(wt + (size_t)brow[i]*EMBED + k1 + kc*8);
            }
        }
        bf16x8 af[4], bfr[4];
        #pragma unroll
        for (int mt = 0; mt < 4; ++mt)
            af[mt] = *reinterpret_cast<const bf16x8*>(&xs[(mh*64 + mt*16 + low)*GSTR + quad*8]);
        #pragma unroll
        for (int t = 0; t < 4; ++t)
            bfr[t] = *reinterpret_cast<const bf16x8*>(&bt[(nh*64 + t*16 + low)*GSTR + quad*8]);
        #pragma unroll
        for (int t = 0; t < 4; ++t)
            #pragma unroll
            for (int mt = 0; mt < 4; ++mt)
                acc[mt][t] = MFMA_BF16(af[mt], bfr[t], acc[mt][t]);
    }

    #pragma unroll
    for (int t = 0; t < 4; ++t){
        const int n = n0 + t*16 + low;
        const float bias = bo[n];
        #pragma unroll
        for (int mt = 0; mt < 4; ++mt)
            #pragma unroll
            for (int r = 0; r < 4; ++r){
                const int m = mw0 + mt*16 + quad*4 + r;
                if (m < MTOT) out[(size_t)m*EMBED + n] = acc[mt][t][r] + bias;
            }
    }
}

extern "C" void kernel_launch(void* const* d_in, const int* in_sizes, int n_in,
                              void* d_out, int out_size, void* d_ws, size_t ws_size,
                              hipStream_t stream)
{
    const float* x  = (const float*)d_in[0];
    const float* Wq = (const float*)d_in[1];
    const float* Wk = (const float*)d_in[2];
    const float* Wv = (const float*)d_in[3];
    const float* Wo = (const float*)d_in[4];
    const float* bo = (const float*)d_in[5];
    float* out = (float*)d_out;

    const size_t NE = (size_t)MTOT * EMBED;
    const size_t VT = (size_t)BATCH*HEADS*HD*SEQP;
    char* ws = (char*)d_ws;
    size_t off = 0;
    __hip_bfloat16* qbuf = (__hip_bfloat16*)(ws + off); off += 2*NE;
    __hip_bfloat16* kbuf = (__hip_bfloat16*)(ws + off); off += 2*NE;
    __hip_bfloat16* abuf = (__hip_bfloat16*)(ws + off); off += 2*NE;
    __hip_bfloat16* vbuf = (__hip_bfloat16*)(ws + off); off += 2*NE;
    __hip_bfloat16* xbuf = (__hip_bfloat16*)(ws + off); off += 2*NE;
    __hip_bfloat16* vt   = (__hip_bfloat16*)(ws + off); off += 2*VT;
    __hip_bfloat16* Wt   = (__hip_bfloat16*)(ws + off); off += (size_t)4*EMBED*EMBED*2;
    float* cos_t = (float*)(ws + off); off += (size_t)SEQ*HEADS*NF*4;
    float* sin_t = (float*)(ws + off); off += (size_t)SEQ*HEADS*NF*4;

    x_to_bf16_kernel<<<dim3((MTOT*EMBED/4 + 255)/256), dim3(256), 0, stream>>>(x, xbuf);
    transpose_w_kernel<<<dim3(6,6,4), dim3(256), 0, stream>>>(Wq, Wk, Wv, Wo, Wt);
    rope_tables_kernel<<<dim3((SEQ*HEADS*NF + 255)/256), dim3(256), 0, stream>>>(cos_t, sin_t);
    qkv_rope_kernel<<<dim3((MTOT + 127)/128, 9), dim3(256), 0, stream>>>(xbuf, Wt, cos_t, sin_t, qbuf, kbuf, vbuf);
    vt_transpose_kernel<<<dim3(96, 17), dim3(256), 0, stream>>>(vbuf, vt);
    attn_kernel<<<dim3(864), dim3(256), 0, stream>>>(qbuf, kbuf, vt, abuf);
    outproj_kernel<<<dim3((MTOT + 127)/128, 3), dim3(256), 0, stream>>>(abuf, Wt, bo, out);
}

// Round 10
// 254.485 us; speedup vs baseline: 1.2049x; 1.1175x over previous
//
#include <hip/hip_runtime.h>
#include <hip/hip_bf16.h>
#include <math.h>

#define EMBED 384
#define HEADS 6
#define HD    64
#define NF    32
#define SEQ   1025
#define SEQP  1088   // padded key stride for Vt (17*64)
#define BATCH 16
#define MTOT  (BATCH*SEQ)   // 16400
#define NCHUNK 17
#define LSTRIDE 72   // attn LDS row stride (elems)
#define GSTR 40      // outproj GEMM LDS row stride (elems)

typedef __bf16 bf16x8 __attribute__((ext_vector_type(8)));
typedef __bf16 bf16x4 __attribute__((ext_vector_type(4)));
typedef float  f32x4  __attribute__((ext_vector_type(4)));

#define MFMA_BF16(A,B,C) __builtin_amdgcn_mfma_f32_16x16x32_bf16((A),(B),(C),0,0,0)

__device__ __forceinline__ __bf16 f2bf(float f){
    __hip_bfloat16 h = __float2bfloat16(f);
    return *reinterpret_cast<__bf16*>(&h);
}

// ---------------- x fp32 -> bf16 prepass ----------------
__global__ __launch_bounds__(256) void x_to_bf16_kernel(
    const float* __restrict__ x, __hip_bfloat16* __restrict__ xb)
{
    const int n4 = MTOT*EMBED/4;
    int i = blockIdx.x*256 + threadIdx.x;
    if (i < n4){
        float4 v = *reinterpret_cast<const float4*>(x + (size_t)i*4);
        bf16x4 b; b[0]=f2bf(v.x); b[1]=f2bf(v.y); b[2]=f2bf(v.z); b[3]=f2bf(v.w);
        *reinterpret_cast<bf16x4*>(reinterpret_cast<__bf16*>(xb) + (size_t)i*4) = b;
    }
}

// ---------------- weight transpose: W fp32 [k][n] -> Wt bf16 [mat][n][k] ----
__global__ __launch_bounds__(256) void transpose_w_kernel(
    const float* __restrict__ Wq, const float* __restrict__ Wk,
    const float* __restrict__ Wv, const float* __restrict__ Wo,
    __hip_bfloat16* __restrict__ Wt)
{
    __shared__ float tile[64][65];
    const int mat = blockIdx.z;
    const float* W = (mat==0)?Wq:(mat==1)?Wk:(mat==2)?Wv:Wo;
    const int k0 = blockIdx.x*64, n0 = blockIdx.y*64;
    const int c = threadIdx.x & 63, rq = threadIdx.x >> 6;
    #pragma unroll
    for (int i = 0; i < 16; ++i){
        int row = rq*16 + i;
        tile[row][c] = W[(size_t)(k0+row)*EMBED + n0 + c];
    }
    __syncthreads();
    #pragma unroll
    for (int i = 0; i < 16; ++i){
        int nr = rq*16 + i;
        Wt[((size_t)mat*EMBED + n0 + nr)*EMBED + k0 + c] = __float2bfloat16(tile[c][nr]);
    }
}

// fp32 erfinv (Giles 2010)
__device__ __forceinline__ float erfinv_f(float x){
    float w = -log1pf(-x*x);
    float p;
    if (w < 5.0f){
        w -= 2.5f;
        p = 2.81022636e-08f;
        p = fmaf(p, w, 3.43273939e-07f);
        p = fmaf(p, w, -3.5233877e-06f);
        p = fmaf(p, w, -4.39150654e-06f);
        p = fmaf(p, w, 0.00021858087f);
        p = fmaf(p, w, -0.00125372503f);
        p = fmaf(p, w, -0.00417768164f);
        p = fmaf(p, w, 0.246640727f);
        p = fmaf(p, w, 1.50140941f);
    } else {
        w = sqrtf(w) - 3.0f;
        p = -0.000200214257f;
        p = fmaf(p, w, 0.000100950558f);
        p = fmaf(p, w, 0.00134934322f);
        p = fmaf(p, w, -0.00367342844f);
        p = fmaf(p, w, 0.00573950773f);
        p = fmaf(p, w, -0.0076224613f);
        p = fmaf(p, w, 0.00943887047f);
        p = fmaf(p, w, 1.00167406f);
        p = fmaf(p, w, 2.83297682f);
    }
    return p * x;
}

__global__ void rope_tables_kernel(float* __restrict__ cos_t, float* __restrict__ sin_t){
    int idx = blockIdx.x * blockDim.x + threadIdx.x;
    if (idx >= SEQ*HEADS*NF) return;
    int f  = idx & (NF-1);
    int hf = idx / NF;
    int h  = hf % HEADS;
    int s  = hf / HEADS;

    double xd = 2.0;
    #pragma unroll
    for (int it = 0; it < 10; ++it) xd = cbrt(1.0 + xd);
    float a1 = (float)(1.0 / xd);
    float a2 = a1 * a1;

    float fi = (float)(h*NF + f + 1);
    float z1 = fmodf(fi * a1, 1.0f);
    float z2 = fmodf(fi * a2, 1.0f);
    float d1 = erfinv_f(2.0f*z1 - 1.0f);
    float d2 = erfinv_f(2.0f*z2 - 1.0f);
    float inv = 1.0f / sqrtf(d1*d1 + d2*d2);
    d1 *= inv; d2 *= inv;

    float omega = 0.1f * powf(10000.0f, (float)f / 31.0f);
    float fx = d1 * omega, fy = d2 * omega;

    float cx = 0.0f, cy = 0.0f;
    if (s > 0){
        int pi = s - 1;
        cx = (float)(pi & 31) / 31.0f * 2.0f - 1.0f;
        cy = (float)(pi >> 5) / 31.0f * 2.0f - 1.0f;
    }
    float theta = fx*cx + fy*cy;
    float sv, cv;
    sincosf(theta, &sv, &cv);
    cos_t[idx] = cv;
    sin_t[idx] = sv;
}

// QKV as C^T = Wt . xb^T: zero LDS, zero barriers, fully unrolled K-loop.
// grid (18 = n-slice, 65 = m-block), block 256 (4 waves = 4 m-tiles of 64).
// Wave tile: 64 n (one head-slice of one matrix) x 64 m. Both operands read
// direct from global in MFMA fragment layout (row-major over k).
// q gets 1/8*log2(e) folded in (attn uses exp2).
__global__ __launch_bounds__(256) void qkv_rope_kernel(
    const __hip_bfloat16* __restrict__ xb_,
    const __hip_bfloat16* __restrict__ Wt,
    const float* __restrict__ cos_t,
    const float* __restrict__ sin_t,
    __hip_bfloat16* __restrict__ qbuf,
    __hip_bfloat16* __restrict__ kbuf,
    __hip_bfloat16* __restrict__ vbuf)
{
    const int tid = threadIdx.x;
    const int w = tid >> 6;
    const int lane = tid & 63;
    const int quad = lane >> 4, low = lane & 15;
    const int n64 = blockIdx.x;              // 0..17, block-uniform
    const int mat = n64 / 6, h = n64 % 6;
    const int m0 = blockIdx.y*256 + w*64;
    const __bf16* xb = reinterpret_cast<const __bf16*>(xb_);
    const __bf16* wt = reinterpret_cast<const __bf16*>(Wt);
    const int nbase = n64*64;

    int mrow[4];
    #pragma unroll
    for (int mt = 0; mt < 4; ++mt){
        int m = m0 + mt*16 + low;
        mrow[mt] = (m > MTOT-1) ? MTOT-1 : m;
    }

    f32x4 acc[4][4] = {};   // [t = n-tile][mt = m-tile]; C^T: row=n, col=m
    #pragma unroll
    for (int kb = 0; kb < 12; ++kb){
        const int k0 = kb*32;
        bf16x8 af[4], bf_[4];
        #pragma unroll
        for (int t = 0; t < 4; ++t)
            af[t] = *reinterpret_cast<const bf16x8*>(
                wt + (size_t)(nbase + t*16 + low)*EMBED + k0 + quad*8);
        #pragma unroll
        for (int mt = 0; mt < 4; ++mt)
            bf_[mt] = *reinterpret_cast<const bf16x8*>(
                xb + (size_t)mrow[mt]*EMBED + k0 + quad*8);
        #pragma unroll
        for (int t = 0; t < 4; ++t)
            #pragma unroll
            for (int mt = 0; mt < 4; ++mt)
                acc[t][mt] = MFMA_BF16(af[t], bf_[mt], acc[t][mt]);
    }

    // epilogue: lane holds col m (one per mt), rows n = quad*4+r contiguous
    if (mat == 2){
        #pragma unroll
        for (int mt = 0; mt < 4; ++mt){
            int m = m0 + mt*16 + low;
            if (m < MTOT){
                int b = m / SEQ, s = m % SEQ;
                __bf16* vb = reinterpret_cast<__bf16*>(vbuf) + ((size_t)(b*HEADS + h)*SEQ + s)*HD;
                #pragma unroll
                for (int t = 0; t < 4; ++t){
                    bf16x4 pk;
                    #pragma unroll
                    for (int r = 0; r < 4; ++r) pk[r] = f2bf(acc[t][mt][r]);
                    *reinterpret_cast<bf16x4*>(vb + t*16 + quad*4) = pk;
                }
            }
        }
    } else {
        __hip_bfloat16* ob = (mat == 0) ? qbuf : kbuf;
        const float qs_ = (mat == 0) ? 0.125f*1.44269504089f : 1.0f;
        #pragma unroll
        for (int mt = 0; mt < 4; ++mt){
            int m = m0 + mt*16 + low;
            if (m < MTOT){
                int b = m / SEQ, s = m % SEQ;
                __bf16* op = reinterpret_cast<__bf16*>(ob) + ((size_t)(b*HEADS + h)*SEQ + s)*HD;
                const int tb = (s*HEADS + h)*NF;
                #pragma unroll
                for (int t = 0; t < 2; ++t){
                    const int f0 = t*16 + quad*4;
                    f32x4 cv = *reinterpret_cast<const f32x4*>(cos_t + tb + f0);
                    f32x4 sv = *reinterpret_cast<const f32x4*>(sin_t + tb + f0);
                    bf16x4 o1, o2;
                    #pragma unroll
                    for (int r = 0; r < 4; ++r){
                        float x1 = acc[t][mt][r];
                        float y1 = acc[t+2][mt][r];
                        o1[r] = f2bf((x1*cv[r] - y1*sv[r])*qs_);
                        o2[r] = f2bf((x1*sv[r] + y1*cv[r])*qs_);
                    }
                    *reinterpret_cast<bf16x4*>(op + f0)      = o1;
                    *reinterpret_cast<bf16x4*>(op + NF + f0) = o2;
                }
            }
        }
    }
}

// V [bh][s][d] -> Vt [bh][d][SEQP]. grid (96, 17), block 256.
__global__ __launch_bounds__(256) void vt_transpose_kernel(
    const __hip_bfloat16* __restrict__ v, __hip_bfloat16* __restrict__ vt)
{
    __shared__ __bf16 tileT[64*72];
    const int tid = threadIdx.x;
    const int bh = blockIdx.x;
    const int s0 = blockIdx.y * 64;
    const __bf16* vb = reinterpret_cast<const __bf16*>(v) + (size_t)bh*SEQ*HD;
    #pragma unroll
    for (int i = 0; i < 2; ++i){
        int ch = tid + i*256;
        int srow = ch >> 3, dg = ch & 7;
        int s = s0 + srow; if (s > SEQ-1) s = SEQ-1;
        bf16x8 val = *reinterpret_cast<const bf16x8*>(vb + (size_t)s*HD + dg*8);
        #pragma unroll
        for (int e = 0; e < 8; ++e)
            tileT[(dg*8 + e)*72 + srow] = val[e];
    }
    __syncthreads();
    __bf16* ot = reinterpret_cast<__bf16*>(vt) + (size_t)bh*HD*SEQP;
    #pragma unroll
    for (int i = 0; i < 2; ++i){
        int ch = tid + i*256;
        int d = ch >> 3, sg = ch & 7;
        bf16x8 val = *reinterpret_cast<const bf16x8*>(&tileT[d*72 + sg*8]);
        *reinterpret_cast<bf16x8*>(ot + (size_t)d*SEQP + s0 + sg*8) = val;
    }
}

// Flash attention (R7 structure): K/V single-buffer LDS staging with
// register prefetch, 2 barriers/chunk; S^T = K.Q^T, O^T = Vt.P^T;
// fixed-base exp2 softmax (log2e folded into q), tree-reduced l.
__global__ __launch_bounds__(256, 4) void attn_kernel(
    const __hip_bfloat16* __restrict__ qbuf,
    const __hip_bfloat16* __restrict__ kbuf,
    const __hip_bfloat16* __restrict__ vtbuf,
    __hip_bfloat16* __restrict__ aout)
{
    __shared__ __align__(16) __bf16 kls[64*LSTRIDE];    // [key][feat]
    __shared__ __align__(16) __bf16 vls[64*LSTRIDE];    // [d][key]
    __shared__ __align__(16) __bf16 pls[4][32*LSTRIDE]; // [w][qrow][key]
    const int tid  = threadIdx.x;
    const int w    = tid >> 6;
    const int lane = tid & 63;
    const int quad = lane >> 4, low = lane & 15;
    const int id = blockIdx.x;
    const int bh = id % 96;
    const int qt = id / 96;
    const int b = bh / HEADS, h = bh % HEADS;
    const __bf16* qb = reinterpret_cast<const __bf16*>(qbuf);
    const __bf16* kb = reinterpret_cast<const __bf16*>(kbuf);
    const __bf16* vt = reinterpret_cast<const __bf16*>(vtbuf);
    const size_t base   = (size_t)bh * SEQ * HD;
    const size_t vtbase = (size_t)bh * HD * SEQP;
    const int q0 = qt*128 + w*32;

    int srow[2], sgk[2], soff[2];
    #pragma unroll
    for (int i = 0; i < 2; ++i){
        int ch = tid + i*256;
        srow[i] = ch >> 3; sgk[i] = ch & 7;
        soff[i] = srow[i]*LSTRIDE + sgk[i]*8;
    }

    bf16x8 bq[2][2];
    #pragma unroll
    for (int nt = 0; nt < 2; ++nt){
        int qs = q0 + nt*16 + low; if (qs > SEQ-1) qs = SEQ-1;
        #pragma unroll
        for (int ks = 0; ks < 2; ++ks)
            bq[nt][ks] = *reinterpret_cast<const bf16x8*>(qb + base + (size_t)qs*HD + ks*32 + quad*8);
    }

    // prefetch chunk 0 staging granules into registers
    bf16x8 kr[2], vr[2];
    #pragma unroll
    for (int i = 0; i < 2; ++i){
        int kk = srow[i]; if (kk > SEQ-1) kk = SEQ-1;
        kr[i] = *reinterpret_cast<const bf16x8*>(kb + base + (size_t)kk*HD + sgk[i]*8);
        vr[i] = *reinterpret_cast<const bf16x8*>(vt + vtbase + (size_t)srow[i]*SEQP + sgk[i]*8);
    }

    f32x4 o[4][2] = {};
    float l_i[2] = {0.f, 0.f};

    for (int c = 0; c < NCHUNK; ++c){
        const int c0 = c*64;
        __syncthreads();   // previous chunk's LDS reads complete
        #pragma unroll
        for (int i = 0; i < 2; ++i){
            *reinterpret_cast<bf16x8*>(&kls[soff[i]]) = kr[i];
            *reinterpret_cast<bf16x8*>(&vls[soff[i]]) = vr[i];
        }
        __syncthreads();
        if (c + 1 < NCHUNK){
            const int c1 = c0 + 64;
            #pragma unroll
            for (int i = 0; i < 2; ++i){
                int kk = c1 + srow[i]; if (kk > SEQ-1) kk = SEQ-1;
                kr[i] = *reinterpret_cast<const bf16x8*>(kb + base + (size_t)kk*HD + sgk[i]*8);
                vr[i] = *reinterpret_cast<const bf16x8*>(vt + vtbase + (size_t)srow[i]*SEQP + c1 + sgk[i]*8);
            }
        }
        // ---- S^T = K.Q^T from LDS K frags
        f32x4 st[4][2] = {};
        #pragma unroll
        for (int kt = 0; kt < 4; ++kt)
            #pragma unroll
            for (int ks = 0; ks < 2; ++ks){
                bf16x8 ak = *reinterpret_cast<const bf16x8*>(&kls[(kt*16 + low)*LSTRIDE + ks*32 + quad*8]);
                #pragma unroll
                for (int nt = 0; nt < 2; ++nt)
                    st[kt][nt] = MFMA_BF16(ak, bq[nt][ks], st[kt][nt]);
            }
        // ---- mask (last chunk only)
        if (c0 + 64 > SEQ){
            #pragma unroll
            for (int kt = 0; kt < 4; ++kt)
                #pragma unroll
                for (int r = 0; r < 4; ++r){
                    int key = c0 + kt*16 + quad*4 + r;
                    if (key >= SEQ){ st[kt][0][r] = -1e30f; st[kt][1][r] = -1e30f; }
                }
        }
        // ---- exp2 + tree-reduced l partial
        #pragma unroll
        for (int nt = 0; nt < 2; ++nt){
            #pragma unroll
            for (int kt = 0; kt < 4; ++kt)
                #pragma unroll
                for (int r = 0; r < 4; ++r)
                    st[kt][nt][r] = exp2f(st[kt][nt][r]);
            f32x4 ps = (st[0][nt] + st[1][nt]) + (st[2][nt] + st[3][nt]);
            l_i[nt] += (ps[0] + ps[1]) + (ps[2] + ps[3]);
        }
        // ---- P^T -> per-wave LDS
        #pragma unroll
        for (int nt = 0; nt < 2; ++nt)
            #pragma unroll
            for (int kt = 0; kt < 4; ++kt){
                bf16x4 pk;
                pk[0] = f2bf(st[kt][nt][0]); pk[1] = f2bf(st[kt][nt][1]);
                pk[2] = f2bf(st[kt][nt][2]); pk[3] = f2bf(st[kt][nt][3]);
                *reinterpret_cast<bf16x4*>(&pls[w][(nt*16 + low)*LSTRIDE + kt*16 + quad*4]) = pk;
            }
        asm volatile("s_waitcnt lgkmcnt(0)" ::: "memory");
        // ---- O^T += Vt.P^T
        #pragma unroll
        for (int ks2 = 0; ks2 < 2; ++ks2){
            bf16x8 bp[2];
            #pragma unroll
            for (int nt = 0; nt < 2; ++nt)
                bp[nt] = *reinterpret_cast<const bf16x8*>(&pls[w][(nt*16 + low)*LSTRIDE + ks2*32 + quad*8]);
            #pragma unroll
            for (int dt = 0; dt < 4; ++dt){
                bf16x8 av = *reinterpret_cast<const bf16x8*>(&vls[(dt*16 + low)*LSTRIDE + ks2*32 + quad*8]);
                #pragma unroll
                for (int nt = 0; nt < 2; ++nt)
                    o[dt][nt] = MFMA_BF16(av, bp[nt], o[dt][nt]);
            }
        }
    }

    #pragma unroll
    for (int nt = 0; nt < 2; ++nt){
        l_i[nt] += __shfl_xor(l_i[nt], 16, 64);
        l_i[nt] += __shfl_xor(l_i[nt], 32, 64);
    }
    #pragma unroll
    for (int nt = 0; nt < 2; ++nt){
        int s = q0 + nt*16 + low;
        if (s < SEQ){
            float inv = 1.0f / l_i[nt];
            #pragma unroll
            for (int dt = 0; dt < 4; ++dt){
                bf16x4 ov;
                #pragma unroll
                for (int r = 0; r < 4; ++r) ov[r] = f2bf(o[dt][nt][r]*inv);
                *reinterpret_cast<bf16x4*>(
                    reinterpret_cast<__bf16*>(aout) + ((size_t)b*SEQ + s)*EMBED + h*HD + dt*16 + quad*4) = ov;
            }
        }
    }
}

// out = attn @ Wo + bo, 128x128 tiles. grid (129, 3), block 256.
__global__ __launch_bounds__(256, 3) void outproj_kernel(
    const __hip_bfloat16* __restrict__ a,
    const __hip_bfloat16* __restrict__ Wt,
    const float* __restrict__ bo,
    float* __restrict__ out)
{
    __shared__ __align__(16) __bf16 xs[128*GSTR];
    __shared__ __align__(16) __bf16 bt[128*GSTR];
    const int tid = threadIdx.x;
    const int m0 = blockIdx.x * 128;
    const int j  = blockIdx.y;
    const __bf16* ab = reinterpret_cast<const __bf16*>(a);
    const __bf16* wt = reinterpret_cast<const __bf16*>(Wt) + (size_t)3*EMBED*EMBED;

    int soff[2], arow[2], brow[2];
    #pragma unroll
    for (int i = 0; i < 2; ++i){
        int g = tid + i*256;
        int row = g >> 2, kc = g & 3;
        soff[i] = row*GSTR + kc*8;
        int am = m0 + row; if (am > MTOT-1) am = MTOT-1;
        arow[i] = am;
        brow[i] = j*128 + row;
    }
    bf16x8 ar[2], br[2];
    #pragma unroll
    for (int i = 0; i < 2; ++i){
        int g = tid + i*256, kc = g & 3;
        ar[i] = *reinterpret_cast<const bf16x8*>(ab + (size_t)arow[i]*EMBED + kc*8);
        br[i] = *reinterpret_cast<const bf16x8*>(wt + (size_t)brow[i]*EMBED + kc*8);
    }

    const int w = tid >> 6;
    const int lane = tid & 63;
    const int quad = lane >> 4, low = lane & 15;
    const int mh = w >> 1, nh = w & 1;
    const int mw0 = m0 + mh*64;
    const int n0 = j*128 + nh*64;

    f32x4 acc[4][4] = {};
    for (int kb = 0; kb < 12; ++kb){
        __syncthreads();
        #pragma unroll
        for (int i = 0; i < 2; ++i){
            *reinterpret_cast<bf16x8*>(&xs[soff[i]]) = ar[i];
            *reinterpret_cast<bf16x8*>(&bt[soff[i]]) = br[i];
        }
        __syncthreads();
        if (kb < 11){
            const int k1 = (kb+1)*32;
            #pragma unroll
            for (int i = 0; i < 2; ++i){
                int g = tid + i*256, kc = g & 3;
                ar[i] = *reinterpret_cast<const bf16x8*>(ab + (size_t)arow[i]*EMBED + k1 + kc*8);
                br[i] = *reinterpret_cast<const bf16x8*>(wt + (size_t)brow[i]*EMBED + k1 + kc*8);
            }
        }
        bf16x8 af[4], bfr[4];
        #pragma unroll
        for (int mt = 0; mt < 4; ++mt)
            af[mt] = *reinterpret_cast<const bf16x8*>(&xs[(mh*64 + mt*16 + low)*GSTR + quad*8]);
        #pragma unroll
        for (int t = 0; t < 4; ++t)
            bfr[t] = *reinterpret_cast<const bf16x8*>(&bt[(nh*64 + t*16 + low)*GSTR + quad*8]);
        #pragma unroll
        for (int t = 0; t < 4; ++t)
            #pragma unroll
            for (int mt = 0; mt < 4; ++mt)
                acc[mt][t] = MFMA_BF16(af[mt], bfr[t], acc[mt][t]);
    }

    #pragma unroll
    for (int t = 0; t < 4; ++t){
        const int n = n0 + t*16 + low;
        const float bias = bo[n];
        #pragma unroll
        for (int mt = 0; mt < 4; ++mt)
            #pragma unroll
            for (int r = 0; r < 4; ++r){
                const int m = mw0 + mt*16 + quad*4 + r;
                if (m < MTOT) out[(size_t)m*EMBED + n] = acc[mt][t][r] + bias;
            }
    }
}

extern "C" void kernel_launch(void* const* d_in, const int* in_sizes, int n_in,
                              void* d_out, int out_size, void* d_ws, size_t ws_size,
                              hipStream_t stream)
{
    const float* x  = (const float*)d_in[0];
    const float* Wq = (const float*)d_in[1];
    const float* Wk = (const float*)d_in[2];
    const float* Wv = (const float*)d_in[3];
    const float* Wo = (const float*)d_in[4];
    const float* bo = (const float*)d_in[5];
    float* out = (float*)d_out;

    const size_t NE = (size_t)MTOT * EMBED;
    const size_t VT = (size_t)BATCH*HEADS*HD*SEQP;
    char* ws = (char*)d_ws;
    size_t off = 0;
    __hip_bfloat16* qbuf = (__hip_bfloat16*)(ws + off); off += 2*NE;
    __hip_bfloat16* kbuf = (__hip_bfloat16*)(ws + off); off += 2*NE;
    __hip_bfloat16* abuf = (__hip_bfloat16*)(ws + off); off += 2*NE;
    __hip_bfloat16* vbuf = (__hip_bfloat16*)(ws + off); off += 2*NE;
    __hip_bfloat16* xbuf = (__hip_bfloat16*)(ws + off); off += 2*NE;
    __hip_bfloat16* vt   = (__hip_bfloat16*)(ws + off); off += 2*VT;
    __hip_bfloat16* Wt   = (__hip_bfloat16*)(ws + off); off += (size_t)4*EMBED*EMBED*2;
    float* cos_t = (float*)(ws + off); off += (size_t)SEQ*HEADS*NF*4;
    float* sin_t = (float*)(ws + off); off += (size_t)SEQ*HEADS*NF*4;

    x_to_bf16_kernel<<<dim3((MTOT*EMBED/4 + 255)/256), dim3(256), 0, stream>>>(x, xbuf);
    transpose_w_kernel<<<dim3(6,6,4), dim3(256), 0, stream>>>(Wq, Wk, Wv, Wo, Wt);
    rope_tables_kernel<<<dim3((SEQ*HEADS*NF + 255)/256), dim3(256), 0, stream>>>(cos_t, sin_t);
    qkv_rope_kernel<<<dim3(18, (MTOT + 255)/256), dim3(256), 0, stream>>>(xbuf, Wt, cos_t, sin_t, qbuf, kbuf, vbuf);
    vt_transpose_kernel<<<dim3(96, 17), dim3(256), 0, stream>>>(vbuf, vt);
    attn_kernel<<<dim3(864), dim3(256), 0, stream>>>(qbuf, kbuf, vt, abuf);
    outproj_kernel<<<dim3((MTOT + 127)/128, 3), dim3(256), 0, stream>>>(abuf, Wt, bo, out);
}

// Round 11
// 216.529 us; speedup vs baseline: 1.4161x; 1.1753x over previous
//
#include <hip/hip_runtime.h>
#include <hip/hip_bf16.h>
#include <math.h>

#define EMBED 384
#define HEADS 6
#define HD    64
#define NF    32
#define SEQ   1025
#define SEQP  1088   // padded key stride for Vt (17*64)
#define BATCH 16
#define MTOT  (BATCH*SEQ)   // 16400
#define NCHUNK 17
#define LSTRIDE 72   // attn LDS row stride (elems)
#define GSTR 40      // GEMM LDS row stride (elems)

typedef __bf16 bf16x8 __attribute__((ext_vector_type(8)));
typedef __bf16 bf16x4 __attribute__((ext_vector_type(4)));
typedef float  f32x4  __attribute__((ext_vector_type(4)));

#define MFMA_BF16(A,B,C) __builtin_amdgcn_mfma_f32_16x16x32_bf16((A),(B),(C),0,0,0)

__device__ __forceinline__ __bf16 f2bf(float f){
    __hip_bfloat16 h = __float2bfloat16(f);
    return *reinterpret_cast<__bf16*>(&h);
}

// ---------------- x fp32 -> bf16 prepass ----------------
__global__ __launch_bounds__(256) void x_to_bf16_kernel(
    const float* __restrict__ x, __hip_bfloat16* __restrict__ xb)
{
    const int n4 = MTOT*EMBED/4;
    int i = blockIdx.x*256 + threadIdx.x;
    if (i < n4){
        float4 v = *reinterpret_cast<const float4*>(x + (size_t)i*4);
        bf16x4 b; b[0]=f2bf(v.x); b[1]=f2bf(v.y); b[2]=f2bf(v.z); b[3]=f2bf(v.w);
        *reinterpret_cast<bf16x4*>(reinterpret_cast<__bf16*>(xb) + (size_t)i*4) = b;
    }
}

// ---------------- weight transpose: W fp32 [k][n] -> Wt bf16 [mat][n][k] ----
__global__ __launch_bounds__(256) void transpose_w_kernel(
    const float* __restrict__ Wq, const float* __restrict__ Wk,
    const float* __restrict__ Wv, const float* __restrict__ Wo,
    __hip_bfloat16* __restrict__ Wt)
{
    __shared__ float tile[64][65];
    const int mat = blockIdx.z;
    const float* W = (mat==0)?Wq:(mat==1)?Wk:(mat==2)?Wv:Wo;
    const int k0 = blockIdx.x*64, n0 = blockIdx.y*64;
    const int c = threadIdx.x & 63, rq = threadIdx.x >> 6;
    #pragma unroll
    for (int i = 0; i < 16; ++i){
        int row = rq*16 + i;
        tile[row][c] = W[(size_t)(k0+row)*EMBED + n0 + c];
    }
    __syncthreads();
    #pragma unroll
    for (int i = 0; i < 16; ++i){
        int nr = rq*16 + i;
        Wt[((size_t)mat*EMBED + n0 + nr)*EMBED + k0 + c] = __float2bfloat16(tile[c][nr]);
    }
}

// fp32 erfinv (Giles 2010)
__device__ __forceinline__ float erfinv_f(float x){
    float w = -log1pf(-x*x);
    float p;
    if (w < 5.0f){
        w -= 2.5f;
        p = 2.81022636e-08f;
        p = fmaf(p, w, 3.43273939e-07f);
        p = fmaf(p, w, -3.5233877e-06f);
        p = fmaf(p, w, -4.39150654e-06f);
        p = fmaf(p, w, 0.00021858087f);
        p = fmaf(p, w, -0.00125372503f);
        p = fmaf(p, w, -0.00417768164f);
        p = fmaf(p, w, 0.246640727f);
        p = fmaf(p, w, 1.50140941f);
    } else {
        w = sqrtf(w) - 3.0f;
        p = -0.000200214257f;
        p = fmaf(p, w, 0.000100950558f);
        p = fmaf(p, w, 0.00134934322f);
        p = fmaf(p, w, -0.00367342844f);
        p = fmaf(p, w, 0.00573950773f);
        p = fmaf(p, w, -0.0076224613f);
        p = fmaf(p, w, 0.00943887047f);
        p = fmaf(p, w, 1.00167406f);
        p = fmaf(p, w, 2.83297682f);
    }
    return p * x;
}

__global__ void rope_tables_kernel(float* __restrict__ cos_t, float* __restrict__ sin_t){
    int idx = blockIdx.x * blockDim.x + threadIdx.x;
    if (idx >= SEQ*HEADS*NF) return;
    int f  = idx & (NF-1);
    int hf = idx / NF;
    int h  = hf % HEADS;
    int s  = hf / HEADS;

    double xd = 2.0;
    #pragma unroll
    for (int it = 0; it < 10; ++it) xd = cbrt(1.0 + xd);
    float a1 = (float)(1.0 / xd);
    float a2 = a1 * a1;

    float fi = (float)(h*NF + f + 1);
    float z1 = fmodf(fi * a1, 1.0f);
    float z2 = fmodf(fi * a2, 1.0f);
    float d1 = erfinv_f(2.0f*z1 - 1.0f);
    float d2 = erfinv_f(2.0f*z2 - 1.0f);
    float inv = 1.0f / sqrtf(d1*d1 + d2*d2);
    d1 *= inv; d2 *= inv;

    float omega = 0.1f * powf(10000.0f, (float)f / 31.0f);
    float fx = d1 * omega, fy = d2 * omega;

    float cx = 0.0f, cy = 0.0f;
    if (s > 0){
        int pi = s - 1;
        cx = (float)(pi & 31) / 31.0f * 2.0f - 1.0f;
        cy = (float)(pi >> 5) / 31.0f * 2.0f - 1.0f;
    }
    float theta = fx*cx + fy*cy;
    float sv, cv;
    sincosf(theta, &sv, &cv);
    cos_t[idx] = cv;
    sin_t[idx] = sv;
}

// QKV: one big GEMM xb[16400x384] @ Wt[1152x384]^T, 128x128 LDS-staged tiles.
// grid (129, 9), block 256 (4 waves, 2x2). Wave = 64 rows x one head's 64 cols.
// q gets 1/8 * log2(e) folded in (attn uses exp2).
__global__ __launch_bounds__(256, 3) void qkv_rope_kernel(
    const __hip_bfloat16* __restrict__ xb_,
    const __hip_bfloat16* __restrict__ Wt,
    const float* __restrict__ cos_t,
    const float* __restrict__ sin_t,
    __hip_bfloat16* __restrict__ qbuf,
    __hip_bfloat16* __restrict__ kbuf,
    __hip_bfloat16* __restrict__ vbuf)
{
    __shared__ __align__(16) __bf16 xs[128*GSTR];
    __shared__ __align__(16) __bf16 bt[128*GSTR];
    const int tid = threadIdx.x;
    const int m0 = blockIdx.x * 128;
    const int j  = blockIdx.y;
    const __bf16* xb = reinterpret_cast<const __bf16*>(xb_);
    const __bf16* wt = reinterpret_cast<const __bf16*>(Wt);

    int soff[2], arow[2], brow[2];
    #pragma unroll
    for (int i = 0; i < 2; ++i){
        int g = tid + i*256;
        int row = g >> 2, kc = g & 3;
        soff[i] = row*GSTR + kc*8;
        int am = m0 + row; if (am > MTOT-1) am = MTOT-1;
        arow[i] = am;
        brow[i] = j*128 + row;
    }

    bf16x8 ar[2], br[2];
    #pragma unroll
    for (int i = 0; i < 2; ++i){
        int g = tid + i*256, kc = g & 3;
        ar[i] = *reinterpret_cast<const bf16x8*>(xb + (size_t)arow[i]*EMBED + kc*8);
        br[i] = *reinterpret_cast<const bf16x8*>(wt + (size_t)brow[i]*EMBED + kc*8);
    }

    const int w = tid >> 6;
    const int lane = tid & 63;
    const int quad = lane >> 4, low = lane & 15;
    const int mh = w >> 1, nh = w & 1;
    const int mw0 = m0 + mh*64;

    f32x4 acc[4][4] = {};
    for (int kb = 0; kb < 12; ++kb){
        __syncthreads();
        #pragma unroll
        for (int i = 0; i < 2; ++i){
            *reinterpret_cast<bf16x8*>(&xs[soff[i]]) = ar[i];
            *reinterpret_cast<bf16x8*>(&bt[soff[i]]) = br[i];
        }
        __syncthreads();
        if (kb < 11){
            const int k1 = (kb+1)*32;
            #pragma unroll
            for (int i = 0; i < 2; ++i){
                int g = tid + i*256, kc = g & 3;
                ar[i] = *reinterpret_cast<const bf16x8*>(xb + (size_t)arow[i]*EMBED + k1 + kc*8);
                br[i] = *reinterpret_cast<const bf16x8*>(wt + (size_t)brow[i]*EMBED + k1 + kc*8);
            }
        }
        bf16x8 af[4], bfr[4];
        #pragma unroll
        for (int mt = 0; mt < 4; ++mt)
            af[mt] = *reinterpret_cast<const bf16x8*>(&xs[(mh*64 + mt*16 + low)*GSTR + quad*8]);
        #pragma unroll
        for (int t = 0; t < 4; ++t)
            bfr[t] = *reinterpret_cast<const bf16x8*>(&bt[(nh*64 + t*16 + low)*GSTR + quad*8]);
        #pragma unroll
        for (int t = 0; t < 4; ++t)
            #pragma unroll
            for (int mt = 0; mt < 4; ++mt)
                acc[mt][t] = MFMA_BF16(af[mt], bfr[t], acc[mt][t]);
    }

    const int n64 = j*2 + nh;
    const int mat = n64 / 6;
    const int h   = n64 % 6;

    if (mat == 2){
        #pragma unroll
        for (int mt = 0; mt < 4; ++mt)
            #pragma unroll
            for (int t = 0; t < 4; ++t)
                #pragma unroll
                for (int r = 0; r < 4; ++r){
                    int m = mw0 + mt*16 + quad*4 + r;
                    if (m < MTOT){
                        int b = m / SEQ, s = m % SEQ;
                        vbuf[((size_t)(b*HEADS + h)*SEQ + s)*HD + t*16 + low] = __float2bfloat16(acc[mt][t][r]);
                    }
                }
    } else {
        __hip_bfloat16* ob = (mat == 0) ? qbuf : kbuf;
        const float qs_ = (mat == 0) ? 0.125f*1.44269504089f : 1.0f;
        #pragma unroll
        for (int mt = 0; mt < 4; ++mt)
            #pragma unroll
            for (int t = 0; t < 2; ++t)
                #pragma unroll
                for (int r = 0; r < 4; ++r){
                    int m = mw0 + mt*16 + quad*4 + r;
                    if (m < MTOT){
                        int b = m / SEQ, s = m % SEQ;
                        int f = t*16 + low;
                        float cv = cos_t[(s*HEADS + h)*NF + f];
                        float sv = sin_t[(s*HEADS + h)*NF + f];
                        float x1 = acc[mt][t][r];
                        float y1 = acc[mt][t+2][r];
                        size_t base = ((size_t)(b*HEADS + h)*SEQ + s)*HD;
                        ob[base + f]      = __float2bfloat16((x1*cv - y1*sv)*qs_);
                        ob[base + NF + f] = __float2bfloat16((x1*sv + y1*cv)*qs_);
                    }
                }
    }
}

// V [bh][s][d] -> Vt [bh][d][SEQP]. grid (96, 17), block 256.
__global__ __launch_bounds__(256) void vt_transpose_kernel(
    const __hip_bfloat16* __restrict__ v, __hip_bfloat16* __restrict__ vt)
{
    __shared__ __bf16 tileT[64*72];
    const int tid = threadIdx.x;
    const int bh = blockIdx.x;
    const int s0 = blockIdx.y * 64;
    const __bf16* vb = reinterpret_cast<const __bf16*>(v) + (size_t)bh*SEQ*HD;
    #pragma unroll
    for (int i = 0; i < 2; ++i){
        int ch = tid + i*256;
        int srow = ch >> 3, dg = ch & 7;
        int s = s0 + srow; if (s > SEQ-1) s = SEQ-1;
        bf16x8 val = *reinterpret_cast<const bf16x8*>(vb + (size_t)s*HD + dg*8);
        #pragma unroll
        for (int e = 0; e < 8; ++e)
            tileT[(dg*8 + e)*72 + srow] = val[e];
    }
    __syncthreads();
    __bf16* ot = reinterpret_cast<__bf16*>(vt) + (size_t)bh*HD*SEQP;
    #pragma unroll
    for (int i = 0; i < 2; ++i){
        int ch = tid + i*256;
        int d = ch >> 3, sg = ch & 7;
        bf16x8 val = *reinterpret_cast<const bf16x8*>(&tileT[d*72 + sg*8]);
        *reinterpret_cast<bf16x8*>(ot + (size_t)d*SEQP + s0 + sg*8) = val;
    }
}

// Flash attention (R7 structure): K/V single-buffer LDS staging with
// register prefetch, 2 barriers/chunk; S^T = K.Q^T, O^T = Vt.P^T;
// fixed-base exp2 softmax (log2e folded into q), tree-reduced l.
__global__ __launch_bounds__(256, 4) void attn_kernel(
    const __hip_bfloat16* __restrict__ qbuf,
    const __hip_bfloat16* __restrict__ kbuf,
    const __hip_bfloat16* __restrict__ vtbuf,
    __hip_bfloat16* __restrict__ aout)
{
    __shared__ __align__(16) __bf16 kls[64*LSTRIDE];    // [key][feat]
    __shared__ __align__(16) __bf16 vls[64*LSTRIDE];    // [d][key]
    __shared__ __align__(16) __bf16 pls[4][32*LSTRIDE]; // [w][qrow][key]
    const int tid  = threadIdx.x;
    const int w    = tid >> 6;
    const int lane = tid & 63;
    const int quad = lane >> 4, low = lane & 15;
    const int id = blockIdx.x;
    const int bh = id % 96;
    const int qt = id / 96;
    const int b = bh / HEADS, h = bh % HEADS;
    const __bf16* qb = reinterpret_cast<const __bf16*>(qbuf);
    const __bf16* kb = reinterpret_cast<const __bf16*>(kbuf);
    const __bf16* vt = reinterpret_cast<const __bf16*>(vtbuf);
    const size_t base   = (size_t)bh * SEQ * HD;
    const size_t vtbase = (size_t)bh * HD * SEQP;
    const int q0 = qt*128 + w*32;

    int srow[2], sgk[2], soff[2];
    #pragma unroll
    for (int i = 0; i < 2; ++i){
        int ch = tid + i*256;
        srow[i] = ch >> 3; sgk[i] = ch & 7;
        soff[i] = srow[i]*LSTRIDE + sgk[i]*8;
    }

    bf16x8 bq[2][2];
    #pragma unroll
    for (int nt = 0; nt < 2; ++nt){
        int qs = q0 + nt*16 + low; if (qs > SEQ-1) qs = SEQ-1;
        #pragma unroll
        for (int ks = 0; ks < 2; ++ks)
            bq[nt][ks] = *reinterpret_cast<const bf16x8*>(qb + base + (size_t)qs*HD + ks*32 + quad*8);
    }

    // prefetch chunk 0 staging granules into registers
    bf16x8 kr[2], vr[2];
    #pragma unroll
    for (int i = 0; i < 2; ++i){
        int kk = srow[i]; if (kk > SEQ-1) kk = SEQ-1;
        kr[i] = *reinterpret_cast<const bf16x8*>(kb + base + (size_t)kk*HD + sgk[i]*8);
        vr[i] = *reinterpret_cast<const bf16x8*>(vt + vtbase + (size_t)srow[i]*SEQP + sgk[i]*8);
    }

    f32x4 o[4][2] = {};
    float l_i[2] = {0.f, 0.f};

    for (int c = 0; c < NCHUNK; ++c){
        const int c0 = c*64;
        __syncthreads();   // previous chunk's LDS reads complete
        #pragma unroll
        for (int i = 0; i < 2; ++i){
            *reinterpret_cast<bf16x8*>(&kls[soff[i]]) = kr[i];
            *reinterpret_cast<bf16x8*>(&vls[soff[i]]) = vr[i];
        }
        __syncthreads();
        if (c + 1 < NCHUNK){
            const int c1 = c0 + 64;
            #pragma unroll
            for (int i = 0; i < 2; ++i){
                int kk = c1 + srow[i]; if (kk > SEQ-1) kk = SEQ-1;
                kr[i] = *reinterpret_cast<const bf16x8*>(kb + base + (size_t)kk*HD + sgk[i]*8);
                vr[i] = *reinterpret_cast<const bf16x8*>(vt + vtbase + (size_t)srow[i]*SEQP + c1 + sgk[i]*8);
            }
        }
        // ---- S^T = K.Q^T from LDS K frags
        f32x4 st[4][2] = {};
        #pragma unroll
        for (int kt = 0; kt < 4; ++kt)
            #pragma unroll
            for (int ks = 0; ks < 2; ++ks){
                bf16x8 ak = *reinterpret_cast<const bf16x8*>(&kls[(kt*16 + low)*LSTRIDE + ks*32 + quad*8]);
                #pragma unroll
                for (int nt = 0; nt < 2; ++nt)
                    st[kt][nt] = MFMA_BF16(ak, bq[nt][ks], st[kt][nt]);
            }
        // ---- mask (last chunk only)
        if (c0 + 64 > SEQ){
            #pragma unroll
            for (int kt = 0; kt < 4; ++kt)
                #pragma unroll
                for (int r = 0; r < 4; ++r){
                    int key = c0 + kt*16 + quad*4 + r;
                    if (key >= SEQ){ st[kt][0][r] = -1e30f; st[kt][1][r] = -1e30f; }
                }
        }
        // ---- exp2 + tree-reduced l partial
        #pragma unroll
        for (int nt = 0; nt < 2; ++nt){
            #pragma unroll
            for (int kt = 0; kt < 4; ++kt)
                #pragma unroll
                for (int r = 0; r < 4; ++r)
                    st[kt][nt][r] = exp2f(st[kt][nt][r]);
            f32x4 ps = (st[0][nt] + st[1][nt]) + (st[2][nt] + st[3][nt]);
            l_i[nt] += (ps[0] + ps[1]) + (ps[2] + ps[3]);
        }
        // ---- P^T -> per-wave LDS
        #pragma unroll
        for (int nt = 0; nt < 2; ++nt)
            #pragma unroll
            for (int kt = 0; kt < 4; ++kt){
                bf16x4 pk;
                pk[0] = f2bf(st[kt][nt][0]); pk[1] = f2bf(st[kt][nt][1]);
                pk[2] = f2bf(st[kt][nt][2]); pk[3] = f2bf(st[kt][nt][3]);
                *reinterpret_cast<bf16x4*>(&pls[w][(nt*16 + low)*LSTRIDE + kt*16 + quad*4]) = pk;
            }
        asm volatile("s_waitcnt lgkmcnt(0)" ::: "memory");
        // ---- O^T += Vt.P^T
        #pragma unroll
        for (int ks2 = 0; ks2 < 2; ++ks2){
            bf16x8 bp[2];
            #pragma unroll
            for (int nt = 0; nt < 2; ++nt)
                bp[nt] = *reinterpret_cast<const bf16x8*>(&pls[w][(nt*16 + low)*LSTRIDE + ks2*32 + quad*8]);
            #pragma unroll
            for (int dt = 0; dt < 4; ++dt){
                bf16x8 av = *reinterpret_cast<const bf16x8*>(&vls[(dt*16 + low)*LSTRIDE + ks2*32 + quad*8]);
                #pragma unroll
                for (int nt = 0; nt < 2; ++nt)
                    o[dt][nt] = MFMA_BF16(av, bp[nt], o[dt][nt]);
            }
        }
    }

    #pragma unroll
    for (int nt = 0; nt < 2; ++nt){
        l_i[nt] += __shfl_xor(l_i[nt], 16, 64);
        l_i[nt] += __shfl_xor(l_i[nt], 32, 64);
    }
    #pragma unroll
    for (int nt = 0; nt < 2; ++nt){
        int s = q0 + nt*16 + low;
        if (s < SEQ){
            float inv = 1.0f / l_i[nt];
            #pragma unroll
            for (int dt = 0; dt < 4; ++dt){
                bf16x4 ov;
                #pragma unroll
                for (int r = 0; r < 4; ++r) ov[r] = f2bf(o[dt][nt][r]*inv);
                *reinterpret_cast<bf16x4*>(
                    reinterpret_cast<__bf16*>(aout) + ((size_t)b*SEQ + s)*EMBED + h*HD + dt*16 + quad*4) = ov;
            }
        }
    }
}

// out = attn @ Wo + bo, 128x128 tiles. grid (129, 3), block 256.
__global__ __launch_bounds__(256, 3) void outproj_kernel(
    const __hip_bfloat16* __restrict__ a,
    const __hip_bfloat16* __restrict__ Wt,
    const float* __restrict__ bo,
    float* __restrict__ out)
{
    __shared__ __align__(16) __bf16 xs[128*GSTR];
    __shared__ __align__(16) __bf16 bt[128*GSTR];
    const int tid = threadIdx.x;
    const int m0 = blockIdx.x * 128;
    const int j  = blockIdx.y;
    const __bf16* ab = reinterpret_cast<const __bf16*>(a);
    const __bf16* wt = reinterpret_cast<const __bf16*>(Wt) + (size_t)3*EMBED*EMBED;

    int soff[2], arow[2], brow[2];
    #pragma unroll
    for (int i = 0; i < 2; ++i){
        int g = tid + i*256;
        int row = g >> 2, kc = g & 3;
        soff[i] = row*GSTR + kc*8;
        int am = m0 + row; if (am > MTOT-1) am = MTOT-1;
        arow[i] = am;
        brow[i] = j*128 + row;
    }
    bf16x8 ar[2], br[2];
    #pragma unroll
    for (int i = 0; i < 2; ++i){
        int g = tid + i*256, kc = g & 3;
        ar[i] = *reinterpret_cast<const bf16x8*>(ab + (size_t)arow[i]*EMBED + kc*8);
        br[i] = *reinterpret_cast<const bf16x8*>(wt + (size_t)brow[i]*EMBED + kc*8);
    }

    const int w = tid >> 6;
    const int lane = tid & 63;
    const int quad = lane >> 4, low = lane & 15;
    const int mh = w >> 1, nh = w & 1;
    const int mw0 = m0 + mh*64;
    const int n0 = j*128 + nh*64;

    f32x4 acc[4][4] = {};
    for (int kb = 0; kb < 12; ++kb){
        __syncthreads();
        #pragma unroll
        for (int i = 0; i < 2; ++i){
            *reinterpret_cast<bf16x8*>(&xs[soff[i]]) = ar[i];
            *reinterpret_cast<bf16x8*>(&bt[soff[i]]) = br[i];
        }
        __syncthreads();
        if (kb < 11){
            const int k1 = (kb+1)*32;
            #pragma unroll
            for (int i = 0; i < 2; ++i){
                int g = tid + i*256, kc = g & 3;
                ar[i] = *reinterpret_cast<const bf16x8*>(ab + (size_t)arow[i]*EMBED + k1 + kc*8);
                br[i] = *reinterpret_cast<const bf16x8*>(wt + (size_t)brow[i]*EMBED + k1 + kc*8);
            }
        }
        bf16x8 af[4], bfr[4];
        #pragma unroll
        for (int mt = 0; mt < 4; ++mt)
            af[mt] = *reinterpret_cast<const bf16x8*>(&xs[(mh*64 + mt*16 + low)*GSTR + quad*8]);
        #pragma unroll
        for (int t = 0; t < 4; ++t)
            bfr[t] = *reinterpret_cast<const bf16x8*>(&bt[(nh*64 + t*16 + low)*GSTR + quad*8]);
        #pragma unroll
        for (int t = 0; t < 4; ++t)
            #pragma unroll
            for (int mt = 0; mt < 4; ++mt)
                acc[mt][t] = MFMA_BF16(af[mt], bfr[t], acc[mt][t]);
    }

    #pragma unroll
    for (int t = 0; t < 4; ++t){
        const int n = n0 + t*16 + low;
        const float bias = bo[n];
        #pragma unroll
        for (int mt = 0; mt < 4; ++mt)
            #pragma unroll
            for (int r = 0; r < 4; ++r){
                const int m = mw0 + mt*16 + quad*4 + r;
                if (m < MTOT) out[(size_t)m*EMBED + n] = acc[mt][t][r] + bias;
            }
    }
}

extern "C" void kernel_launch(void* const* d_in, const int* in_sizes, int n_in,
                              void* d_out, int out_size, void* d_ws, size_t ws_size,
                              hipStream_t stream)
{
    const float* x  = (const float*)d_in[0];
    const float* Wq = (const float*)d_in[1];
    const float* Wk = (const float*)d_in[2];
    const float* Wv = (const float*)d_in[3];
    const float* Wo = (const float*)d_in[4];
    const float* bo = (const float*)d_in[5];
    float* out = (float*)d_out;

    const size_t NE = (size_t)MTOT * EMBED;
    const size_t VT = (size_t)BATCH*HEADS*HD*SEQP;
    char* ws = (char*)d_ws;
    size_t off = 0;
    __hip_bfloat16* qbuf = (__hip_bfloat16*)(ws + off); off += 2*NE;
    __hip_bfloat16* kbuf = (__hip_bfloat16*)(ws + off); off += 2*NE;
    __hip_bfloat16* abuf = (__hip_bfloat16*)(ws + off); off += 2*NE;
    __hip_bfloat16* vbuf = (__hip_bfloat16*)(ws + off); off += 2*NE;
    __hip_bfloat16* xbuf = (__hip_bfloat16*)(ws + off); off += 2*NE;
    __hip_bfloat16* vt   = (__hip_bfloat16*)(ws + off); off += 2*VT;
    __hip_bfloat16* Wt   = (__hip_bfloat16*)(ws + off); off += (size_t)4*EMBED*EMBED*2;
    float* cos_t = (float*)(ws + off); off += (size_t)SEQ*HEADS*NF*4;
    float* sin_t = (float*)(ws + off); off += (size_t)SEQ*HEADS*NF*4;

    x_to_bf16_kernel<<<dim3((MTOT*EMBED/4 + 255)/256), dim3(256), 0, stream>>>(x, xbuf);
    transpose_w_kernel<<<dim3(6,6,4), dim3(256), 0, stream>>>(Wq, Wk, Wv, Wo, Wt);
    rope_tables_kernel<<<dim3((SEQ*HEADS*NF + 255)/256), dim3(256), 0, stream>>>(cos_t, sin_t);
    qkv_rope_kernel<<<dim3((MTOT + 127)/128, 9), dim3(256), 0, stream>>>(xbuf, Wt, cos_t, sin_t, qbuf, kbuf, vbuf);
    vt_transpose_kernel<<<dim3(96, 17), dim3(256), 0, stream>>>(vbuf, vt);
    attn_kernel<<<dim3(864), dim3(256), 0, stream>>>(qbuf, kbuf, vt, abuf);
    outproj_kernel<<<dim3((MTOT + 127)/128, 3), dim3(256), 0, stream>>>(abuf, Wt, bo, out);
}